// Round 1
// baseline (264.404 us; speedup 1.0000x reference)
//
#include <hip/hip_runtime.h>
#include <hip/hip_bf16.h>

#define NN 384
#define DD 128
#define MM (NN*NN)   // 147456 rows

typedef __attribute__((ext_vector_type(8))) short short8;
typedef __attribute__((ext_vector_type(4))) float f32x4;

__device__ __forceinline__ unsigned short f2bf(float f){
  unsigned u = __float_as_uint(f);
  u += 0x7fffu + ((u >> 16) & 1u);      // RNE
  return (unsigned short)(u >> 16);
}
__device__ __forceinline__ float bf2f(unsigned short u){
  return __uint_as_float(((unsigned)u) << 16);
}
__device__ __forceinline__ float sigm(float x){
  return 1.0f / (1.0f + __expf(-x));
}
__device__ __forceinline__ f32x4 mfma16(short8 a, short8 b, f32x4 c){
  return __builtin_amdgcn_mfma_f32_16x16x32_bf16(a, b, c, 0, 0, 0);
}

// ---------------------------------------------------------------------------
// k_prep: Wcat_t[n][k] bf16 = [Wl|Wlg|Wr|Wrg|Wog]^T  (n in [0,640)), and
//         Wot[c][k] bf16 = Wo^T. B-operand fragments read these from L2.
__global__ void k_prep(const float* __restrict__ Wl, const float* __restrict__ Wlg,
                       const float* __restrict__ Wr, const float* __restrict__ Wrg,
                       const float* __restrict__ Wog, const float* __restrict__ Wo,
                       unsigned short* __restrict__ Wcat, unsigned short* __restrict__ Wot){
  int n = blockIdx.x;           // 0..767
  if(n < 640){
    const float* src; int col;
    if(n < 128){ src = Wl;  col = n; }
    else if(n < 256){ src = Wlg; col = n-128; }
    else if(n < 384){ src = Wr;  col = n-256; }
    else if(n < 512){ src = Wrg; col = n-384; }
    else            { src = Wog; col = n-512; }
    for(int k = threadIdx.x; k < 128; k += 64)
      Wcat[n*128 + k] = f2bf(src[k*128 + col]);
  } else {
    int c = n - 640;
    for(int k = threadIdx.x; k < 128; k += 64)
      Wot[c*128 + k] = f2bf(Wo[k*128 + c]);
  }
}

// ---------------------------------------------------------------------------
// k_ln_x: layernorm rows of x (fp32) -> xn bf16.  One wave per row.
__global__ __launch_bounds__(256) void k_ln_x(const float* __restrict__ x,
    const float* __restrict__ na, const float* __restrict__ nb,
    unsigned short* __restrict__ xn){
  int wid = threadIdx.x >> 6, lane = threadIdx.x & 63;
  long r = (long)blockIdx.x*4 + wid;
  float2 v = *(const float2*)(x + r*DD + lane*2);
  float s  = v.x + v.y;
  float sq = v.x*v.x + v.y*v.y;
  #pragma unroll
  for(int m = 32; m >= 1; m >>= 1){ s += __shfl_xor(s, m); sq += __shfl_xor(sq, m); }
  float mean = s  * (1.0f/128.0f);
  float var  = sq * (1.0f/128.0f) - mean*mean;
  float rstd = rsqrtf(var + 1e-5f);
  float2 a = *(const float2*)(na + lane*2);
  float2 b = *(const float2*)(nb + lane*2);
  unsigned pk = (unsigned)f2bf(a.x*(v.x-mean)*rstd + b.x)
              | ((unsigned)f2bf(a.y*(v.y-mean)*rstd + b.y) << 16);
  *(unsigned*)(xn + r*DD + lane*2) = pk;
}

// ---------------------------------------------------------------------------
// k_proj: P = xn @ Wcat (+bias, sigmoid fuse).  blockIdx.y: 0=L 1=R 2=G.
//   L/R tiles: 2-D M-tile rows rl = jj*64+kk  <->  xn row (k0+kk)*384+(j0+jj),
//   epilogue transposes through LDS and writes Lt[d][j][k] / Rt[d][i][k].
//   G tiles: plain 128-row tiles -> gate[r][c].
__global__ __launch_bounds__(512) void k_proj(
    const unsigned short* __restrict__ xn, const unsigned short* __restrict__ Wcat,
    const float* __restrict__ bl, const float* __restrict__ blg,
    const float* __restrict__ br, const float* __restrict__ brg,
    const float* __restrict__ bog,
    unsigned short* __restrict__ Lt, unsigned short* __restrict__ Rt,
    unsigned short* __restrict__ gate){
  __shared__ char lds[32768];           // xn tile, then transpose-out buffer
  const int g = blockIdx.y;
  const int bid = blockIdx.x;           // 0..1151
  int k0 = 0, j0 = 0;
  if(g < 2){ k0 = (bid % 6)*64; j0 = (bid / 6)*2; }

  { // stage xn tile [128 rows][128 k] bf16, XOR-swizzled rows of 256B
    int kb16 = threadIdx.x & 15;
    #pragma unroll
    for(int pass = 0; pass < 4; ++pass){
      int rl = (threadIdx.x >> 4) + pass*32;
      long gr;
      if(g == 2) gr = (long)bid*128 + rl;
      else { int kk = rl & 63, jj = rl >> 6; gr = (long)(k0+kk)*NN + (j0+jj); }
      uint4 v = *(const uint4*)(xn + gr*DD + kb16*8);
      *(uint4*)(&lds[rl*256 + ((kb16*16) ^ ((rl & 7) << 4))]) = v;
    }
  }
  __syncthreads();

  const int wid = threadIdx.x >> 6, lane = threadIdx.x & 63;
  const int wr = wid >> 1, wc = wid & 1;       // 4 row-waves x 2 col-waves
  const int lrow = lane & 15, lgrp = lane >> 4;
  const int nbase = g * 256;
  const int npair = (g == 2) ? 1 : 2;

  f32x4 zero = {0.f, 0.f, 0.f, 0.f};
  f32x4 acc[2][4][2];
  #pragma unroll
  for(int i1 = 0; i1 < 2; ++i1)
    #pragma unroll
    for(int i2 = 0; i2 < 4; ++i2)
      #pragma unroll
      for(int i3 = 0; i3 < 2; ++i3) acc[i1][i2][i3] = zero;

  #pragma unroll
  for(int ks = 0; ks < 4; ++ks){
    short8 af[2];
    #pragma unroll
    for(int fr = 0; fr < 2; ++fr){
      int row = wr*32 + fr*16 + lrow;
      af[fr] = *(const short8*)(&lds[row*256 + ((ks*64 + lgrp*16) ^ ((row & 7) << 4))]);
    }
    #pragma unroll
    for(int fc = 0; fc < 4; ++fc){
      #pragma unroll
      for(int p = 0; p < 2; ++p){
        if(p < npair){
          int n = nbase + p*128 + wc*64 + fc*16 + lrow;
          short8 bf = *(const short8*)(Wcat + n*128 + ks*32 + lgrp*8);
          acc[0][fc][p] = mfma16(af[0], bf, acc[0][fc][p]);
          acc[1][fc][p] = mfma16(af[1], bf, acc[1][fc][p]);
        }
      }
    }
  }
  __syncthreads();   // xn tile dead; LDS reused below

  if(g == 2){
    #pragma unroll
    for(int fr = 0; fr < 2; ++fr)
      #pragma unroll
      for(int fc = 0; fc < 4; ++fc){
        int c = wc*64 + fc*16 + lrow;
        float bias = bog[c];
        #pragma unroll
        for(int q = 0; q < 4; ++q){
          int rl = wr*32 + fr*16 + lgrp*4 + q;
          long m = (long)bid*128 + rl;
          gate[m*DD + c] = f2bf(sigm(acc[fr][fc][0][q] + bias));
        }
      }
    return;
  }

  const float* b0 = (g == 0) ? bl  : br;
  const float* b1 = (g == 0) ? blg : brg;
  unsigned short* dst = (g == 0) ? Lt : Rt;
  #pragma unroll
  for(int fr = 0; fr < 2; ++fr)
    #pragma unroll
    for(int fc = 0; fc < 4; ++fc){
      int c = wc*64 + fc*16 + lrow;
      float bb0 = b0[c], bb1 = b1[c];
      #pragma unroll
      for(int q = 0; q < 4; ++q){
        int rl = wr*32 + fr*16 + lgrp*4 + q;
        float v = (acc[fr][fc][0][q] + bb0) * sigm(acc[fr][fc][1][q] + bb1);
        *(unsigned short*)(&lds[c*256 + ((rl*2) ^ ((c & 7) << 4))]) = f2bf(v);
      }
    }
  __syncthreads();
  { // coalesced write-out: Lt/Rt[d][j0+jj][k0 + kk]  (128B rows of k)
    int d = threadIdx.x >> 2, part = threadIdx.x & 3;
    int jj = part >> 1, kk0 = (part & 1)*32;
    #pragma unroll
    for(int o = 0; o < 32; o += 8){
      int rl = jj*64 + kk0 + o;
      uint4 v = *(const uint4*)(&lds[d*256 + ((rl*2) ^ ((d & 7) << 4))]);
      *(uint4*)(dst + (long)d*MM + (long)(j0+jj)*NN + (k0 + kk0 + o)) = v;
    }
  }
}

// ---------------------------------------------------------------------------
// k_einsum: per channel d: mid[d][i][j] = (1/384) * sum_k Rt[d][i][k]*Lt[d][j][k]
// 128x128 output tile per block, K=384 in 6 staged k-tiles of 64.
__global__ __launch_bounds__(256) void k_einsum(
    const unsigned short* __restrict__ Rt, const unsigned short* __restrict__ Lt,
    unsigned short* __restrict__ mid){
  __shared__ char lds[32768];           // [0,16K): A tile, [16K,32K): B tile
  const int d = blockIdx.y;
  const int it = blockIdx.x / 3, jt = blockIdx.x % 3;
  const int i0 = it*128, j0 = jt*128;
  const unsigned short* Abase = Rt + (long)d*MM;
  const unsigned short* Bbase = Lt + (long)d*MM;
  const int wid = threadIdx.x >> 6, lane = threadIdx.x & 63;
  const int wr = wid >> 1, wc = wid & 1;
  const int lrow = lane & 15, lgrp = lane >> 4;

  f32x4 zero = {0.f, 0.f, 0.f, 0.f};
  f32x4 acc[4][4];
  #pragma unroll
  for(int i1 = 0; i1 < 4; ++i1)
    #pragma unroll
    for(int i2 = 0; i2 < 4; ++i2) acc[i1][i2] = zero;

  for(int kt = 0; kt < 6; ++kt){
    int k = kt*64;
    int kb16 = threadIdx.x & 7;
    int rr0  = threadIdx.x >> 3;
    #pragma unroll
    for(int pass = 0; pass < 8; ++pass){
      int rr = rr0 + pass*32;           // 0..255: first 128 = A rows, rest = B rows
      int r = rr & 127;
      const unsigned short* src = (rr < 128) ? (Abase + (long)(i0+r)*NN + k)
                                             : (Bbase + (long)(j0+r)*NN + k);
      uint4 v = *(const uint4*)(src + kb16*8);
      *(uint4*)(&lds[(rr >> 7)*16384 + r*128 + ((kb16*16) ^ ((r & 7) << 4))]) = v;
    }
    __syncthreads();
    #pragma unroll
    for(int ks = 0; ks < 2; ++ks){
      short8 af[4], bf[4];
      #pragma unroll
      for(int f = 0; f < 4; ++f){
        int ra = wr*64 + f*16 + lrow;
        af[f] = *(const short8*)(&lds[ra*128 + ((ks*64 + lgrp*16) ^ ((ra & 7) << 4))]);
        int rb = wc*64 + f*16 + lrow;
        bf[f] = *(const short8*)(&lds[16384 + rb*128 + ((ks*64 + lgrp*16) ^ ((rb & 7) << 4))]);
      }
      #pragma unroll
      for(int fr = 0; fr < 4; ++fr)
        #pragma unroll
        for(int fc = 0; fc < 4; ++fc)
          acc[fr][fc] = mfma16(af[fr], bf[fc], acc[fr][fc]);
    }
    __syncthreads();
  }
  const float s = 1.0f/384.0f;
  #pragma unroll
  for(int fr = 0; fr < 4; ++fr)
    #pragma unroll
    for(int fc = 0; fc < 4; ++fc){
      int j = j0 + wc*64 + fc*16 + lrow;
      #pragma unroll
      for(int q = 0; q < 4; ++q){
        int i = i0 + wr*64 + fr*16 + lgrp*4 + q;
        mid[(long)d*MM + (long)i*NN + j] = f2bf(acc[fr][fc][q]*s);
      }
    }
}

// ---------------------------------------------------------------------------
// k_final: per (i, 32-wide j strip): gather mid[d][i][j], LN over d, *gate,
//          bf16 MFMA vs Wo^T, +bo, fp32 out.
__global__ __launch_bounds__(256) void k_final(
    const unsigned short* __restrict__ mid, const unsigned short* __restrict__ gate,
    const float* __restrict__ ona, const float* __restrict__ onb,
    const unsigned short* __restrict__ Wot, const float* __restrict__ bo,
    float* __restrict__ out){
  __shared__ float midt[32][129];
  __shared__ char vlds[8192];           // val tile [32 j][128 d] bf16, swizzled
  const int i = blockIdx.y;
  const int j0 = blockIdx.x*32;

  { // gather: 64B contiguous chunks per (d)
    int j = threadIdx.x & 31, dr = threadIdx.x >> 5;
    #pragma unroll
    for(int pass = 0; pass < 16; ++pass){
      int d = dr + pass*8;
      midt[j][d] = bf2f(mid[(long)d*MM + (long)i*NN + j0 + j]);
    }
  }
  __syncthreads();

  { // LN + gate, 8 threads per j-row
    int j = threadIdx.x >> 3, s = threadIdx.x & 7;
    float sum = 0.f, sq = 0.f;
    #pragma unroll
    for(int o = 0; o < 16; ++o){ float v = midt[j][s*16 + o]; sum += v; sq += v*v; }
    #pragma unroll
    for(int m = 1; m < 8; m <<= 1){ sum += __shfl_xor(sum, m); sq += __shfl_xor(sq, m); }
    float mean = sum*(1.f/128.f);
    float var  = sq *(1.f/128.f) - mean*mean;
    float rstd = rsqrtf(var + 1e-5f);
    long gr = ((long)i*NN + j0 + j)*DD;
    #pragma unroll
    for(int o = 0; o < 16; o += 2){
      int dd = s*16 + o;
      unsigned gv = *(const unsigned*)(gate + gr + dd);
      float g0 = bf2f((unsigned short)(gv & 0xffffu));
      float g1 = bf2f((unsigned short)(gv >> 16));
      float v0 = (ona[dd]  *(midt[j][dd]  -mean)*rstd + onb[dd]  )*g0;
      float v1 = (ona[dd+1]*(midt[j][dd+1]-mean)*rstd + onb[dd+1])*g1;
      unsigned pk = (unsigned)f2bf(v0) | ((unsigned)f2bf(v1) << 16);
      *(unsigned*)(&vlds[j*256 + ((dd*2) ^ ((j & 7) << 4))]) = pk;
    }
  }
  __syncthreads();

  const int wid = threadIdx.x >> 6, lane = threadIdx.x & 63;
  const int wr = wid >> 1, wc = wid & 1;
  const int lrow = lane & 15, lgrp = lane >> 4;
  f32x4 zero = {0.f, 0.f, 0.f, 0.f};
  f32x4 acc[4] = {zero, zero, zero, zero};
  #pragma unroll
  for(int ks = 0; ks < 4; ++ks){
    int row = wr*16 + lrow;
    short8 a = *(const short8*)(&vlds[row*256 + ((ks*64 + lgrp*16) ^ ((row & 7) << 4))]);
    #pragma unroll
    for(int fc = 0; fc < 4; ++fc){
      int n = wc*64 + fc*16 + lrow;
      short8 b = *(const short8*)(Wot + n*128 + ks*32 + lgrp*8);
      acc[fc] = mfma16(a, b, acc[fc]);
    }
  }
  #pragma unroll
  for(int fc = 0; fc < 4; ++fc){
    int c = wc*64 + fc*16 + lrow;
    float bb = bo[c];
    #pragma unroll
    for(int q = 0; q < 4; ++q){
      int jl = wr*16 + lgrp*4 + q;
      out[((long)i*NN + j0 + jl)*DD + c] = acc[fc][q] + bb;
    }
  }
}

// ---------------------------------------------------------------------------
extern "C" void kernel_launch(void* const* d_in, const int* in_sizes, int n_in,
                              void* d_out, int out_size, void* d_ws, size_t ws_size,
                              hipStream_t stream){
  const float* x   = (const float*)d_in[0];
  const float* na  = (const float*)d_in[1];
  const float* nb  = (const float*)d_in[2];
  const float* Wl  = (const float*)d_in[3];
  const float* bl  = (const float*)d_in[4];
  const float* Wr  = (const float*)d_in[5];
  const float* br  = (const float*)d_in[6];
  const float* Wlg = (const float*)d_in[7];
  const float* blg = (const float*)d_in[8];
  const float* Wrg = (const float*)d_in[9];
  const float* brg = (const float*)d_in[10];
  const float* Wog = (const float*)d_in[11];
  const float* bog = (const float*)d_in[12];
  const float* ona = (const float*)d_in[13];
  const float* onb = (const float*)d_in[14];
  const float* Wo  = (const float*)d_in[15];
  const float* bo  = (const float*)d_in[16];
  float* out = (float*)d_out;

  char* ws = (char*)d_ws;
  const size_t SZ = (size_t)MM*DD*2;                    // 37.75 MB
  unsigned short* xn   = (unsigned short*)(ws);         // region0 (later: mid)
  unsigned short* Lt   = (unsigned short*)(ws + SZ);
  unsigned short* Rt   = (unsigned short*)(ws + 2*SZ);
  unsigned short* gate = (unsigned short*)(ws + 3*SZ);
  unsigned short* Wcat = (unsigned short*)(ws + 4*SZ);
  unsigned short* Wot  = (unsigned short*)(ws + 4*SZ + (size_t)640*128*2);
  unsigned short* mid  = xn;   // xn dead after k_proj; overlay

  k_prep  <<<768, 64, 0, stream>>>(Wl, Wlg, Wr, Wrg, Wog, Wo, Wcat, Wot);
  k_ln_x  <<<MM/4, 256, 0, stream>>>(x, na, nb, xn);
  k_proj  <<<dim3(1152, 3), 512, 0, stream>>>(xn, Wcat, bl, blg, br, brg, bog, Lt, Rt, gate);
  k_einsum<<<dim3(9, 128), 256, 0, stream>>>(Rt, Lt, mid);
  k_final <<<dim3(12, 384), 256, 0, stream>>>(mid, gate, ona, onb, Wot, bo, out);
}

// Round 2
// 220.359 us; speedup vs baseline: 1.1999x; 1.1999x over previous
//
#include <hip/hip_runtime.h>
#include <hip/hip_bf16.h>

#define NN 384
#define DD 128
#define MM (NN*NN)   // 147456 rows

typedef __attribute__((ext_vector_type(8))) short short8;
typedef __attribute__((ext_vector_type(4))) float f32x4;

__device__ __forceinline__ unsigned short f2bf(float f){
  unsigned u = __float_as_uint(f);
  u += 0x7fffu + ((u >> 16) & 1u);      // RNE
  return (unsigned short)(u >> 16);
}
__device__ __forceinline__ float bf2f(unsigned short u){
  return __uint_as_float(((unsigned)u) << 16);
}
__device__ __forceinline__ float sigm(float x){
  return 1.0f / (1.0f + __expf(-x));
}
__device__ __forceinline__ f32x4 mfma16(short8 a, short8 b, f32x4 c){
  return __builtin_amdgcn_mfma_f32_16x16x32_bf16(a, b, c, 0, 0, 0);
}
// async global->LDS, 16B per lane; lds dest must be wave-uniform base (HW adds lane*16)
__device__ __forceinline__ void gll16(const void* g, void* l){
  __builtin_amdgcn_global_load_lds(
      (const __attribute__((address_space(1))) unsigned int*)g,
      (__attribute__((address_space(3))) unsigned int*)l, 16, 0, 0);
}

// ---------------------------------------------------------------------------
// k_prep: Wcat_t[n][k] bf16 = [Wl|Wlg|Wr|Wrg|Wog]^T  (n in [0,640)), and
//         Wot[c][k] bf16 = Wo^T.
__global__ void k_prep(const float* __restrict__ Wl, const float* __restrict__ Wlg,
                       const float* __restrict__ Wr, const float* __restrict__ Wrg,
                       const float* __restrict__ Wog, const float* __restrict__ Wo,
                       unsigned short* __restrict__ Wcat, unsigned short* __restrict__ Wot){
  int n = blockIdx.x;           // 0..767
  if(n < 640){
    const float* src; int col;
    if(n < 128){ src = Wl;  col = n; }
    else if(n < 256){ src = Wlg; col = n-128; }
    else if(n < 384){ src = Wr;  col = n-256; }
    else if(n < 512){ src = Wrg; col = n-384; }
    else            { src = Wog; col = n-512; }
    for(int k = threadIdx.x; k < 128; k += 64)
      Wcat[n*128 + k] = f2bf(src[k*128 + col]);
  } else {
    int c = n - 640;
    for(int k = threadIdx.x; k < 128; k += 64)
      Wot[c*128 + k] = f2bf(Wo[k*128 + c]);
  }
}

// ---------------------------------------------------------------------------
// k_ln_x: layernorm rows of x (fp32) -> xn bf16.  One wave per row.
__global__ __launch_bounds__(256) void k_ln_x(const float* __restrict__ x,
    const float* __restrict__ na, const float* __restrict__ nb,
    unsigned short* __restrict__ xn){
  int wid = threadIdx.x >> 6, lane = threadIdx.x & 63;
  long r = (long)blockIdx.x*4 + wid;
  float2 v = *(const float2*)(x + r*DD + lane*2);
  float s  = v.x + v.y;
  float sq = v.x*v.x + v.y*v.y;
  #pragma unroll
  for(int m = 32; m >= 1; m >>= 1){ s += __shfl_xor(s, m); sq += __shfl_xor(sq, m); }
  float mean = s  * (1.0f/128.0f);
  float var  = sq * (1.0f/128.0f) - mean*mean;
  float rstd = rsqrtf(var + 1e-5f);
  float2 a = *(const float2*)(na + lane*2);
  float2 b = *(const float2*)(nb + lane*2);
  unsigned pk = (unsigned)f2bf(a.x*(v.x-mean)*rstd + b.x)
              | ((unsigned)f2bf(a.y*(v.y-mean)*rstd + b.y) << 16);
  *(unsigned*)(xn + r*DD + lane*2) = pk;
}

// ---------------------------------------------------------------------------
// k_proj: 64-row tiles, 256 thr (4 col-waves), K=128 one-shot.
//   B frags (16) loaded to regs up-front; A staged via global_load_lds with
//   pre-swizzled source (linear LDS dest, XOR-swizzled reads).
//   g=0: L/Lg -> Lt[d][j][k]; g=1: R/Rg -> Rt[d][i][k]; g=2: Og -> gate[m][c].
__global__ __launch_bounds__(256) void k_proj(
    const unsigned short* __restrict__ xn, const unsigned short* __restrict__ Wcat,
    const float* __restrict__ bl, const float* __restrict__ blg,
    const float* __restrict__ br, const float* __restrict__ brg,
    const float* __restrict__ bog,
    unsigned short* __restrict__ Lt, unsigned short* __restrict__ Rt,
    unsigned short* __restrict__ gate){
  __shared__ char lds[16384];            // A tile [64][256B]; reused by epilogue
  const int g = blockIdx.y;
  const int bid = blockIdx.x;            // 0..2303
  const int wid = threadIdx.x >> 6, lane = threadIdx.x & 63;
  const int lrow = lane & 15, lgrp = lane >> 4;
  const int wc = wid;                    // wave's 32 pair-cols at wc*32
  const int npair = (g == 2) ? 1 : 2;
  const int nb = g * 256;                // 0 / 256 / 512

  // ---- B frags to registers (issued first; latency overlaps A-stage)
  short8 bfrag[2][2][4];                 // [p][fc][ks]
  #pragma unroll
  for(int p = 0; p < 2; ++p)
    #pragma unroll
    for(int fc = 0; fc < 2; ++fc)
      #pragma unroll
      for(int ks = 0; ks < 4; ++ks)
        if(p < npair){
          int n = nb + p*128 + wc*32 + fc*16 + lrow;
          bfrag[p][fc][ks] = *(const short8*)(Wcat + n*128 + ks*32 + lgrp*8);
        }

  // ---- stage A: 64 rows x 256B, inverse-swizzled source -> linear LDS
  {
    int rl4 = lane >> 4, c = lane & 15;
    #pragma unroll
    for(int t = 0; t < 4; ++t){
      int r = wid*16 + t*4 + rl4;
      long gr = (g == 2) ? ((long)bid*64 + r)
                         : ((long)((bid % 6)*64 + r)*NN + (bid / 6));
      gll16(xn + gr*DD + (c ^ (r & 7))*8, &lds[(wid*16 + t*4)*256]);
    }
  }
  __syncthreads();

  // ---- compute
  f32x4 zero = {0.f,0.f,0.f,0.f};
  f32x4 acc[4][2][2];
  #pragma unroll
  for(int a1 = 0; a1 < 4; ++a1)
    #pragma unroll
    for(int a2 = 0; a2 < 2; ++a2)
      #pragma unroll
      for(int a3 = 0; a3 < 2; ++a3) acc[a1][a2][a3] = zero;

  #pragma unroll
  for(int ks = 0; ks < 4; ++ks){
    short8 af[4];
    #pragma unroll
    for(int fr = 0; fr < 4; ++fr){
      int r = fr*16 + lrow;
      af[fr] = *(const short8*)(&lds[r*256 + (((ks*4 + lgrp)*16) ^ ((r & 7) << 4))]);
    }
    #pragma unroll
    for(int fr = 0; fr < 4; ++fr)
      #pragma unroll
      for(int fc = 0; fc < 2; ++fc){
        acc[fr][fc][0] = mfma16(af[fr], bfrag[0][fc][ks], acc[fr][fc][0]);
        if(npair == 2)
          acc[fr][fc][1] = mfma16(af[fr], bfrag[1][fc][ks], acc[fr][fc][1]);
      }
  }
  __syncthreads();   // A tile dead; LDS reused

  if(g == 2){
    // gate: LDS repack [64 rows][128 c], then coalesced 256B-row writes
    #pragma unroll
    for(int fr = 0; fr < 4; ++fr)
      #pragma unroll
      for(int fc = 0; fc < 2; ++fc){
        int c = wc*32 + fc*16 + lrow;
        float bias = bog[c];
        #pragma unroll
        for(int q = 0; q < 4; ++q){
          int rl = fr*16 + lgrp*4 + q;
          *(unsigned short*)(&lds[rl*256 + ((c*2) ^ ((rl & 7) << 4))])
              = f2bf(sigm(acc[fr][fc][0][q] + bias));
        }
      }
    __syncthreads();
    int rl = threadIdx.x >> 2, q4 = threadIdx.x & 3;
    #pragma unroll
    for(int t = 0; t < 4; ++t){
      int ch = t*4 + q4;                 // 4 lanes -> 64B contiguous
      uint4 v = *(const uint4*)(&lds[rl*256 + ((ch*16) ^ ((rl & 7) << 4))]);
      *(uint4*)(gate + ((long)bid*64 + rl)*DD + ch*8) = v;
    }
    return;
  }

  // L/R: bias + sigmoid-gate fuse, LDS transpose [128 c][64 rl], write [d][j][k]
  const float* b0 = (g == 0) ? bl  : br;
  const float* b1 = (g == 0) ? blg : brg;
  unsigned short* dst = (g == 0) ? Lt : Rt;
  const int j0 = bid / 6, k0 = (bid % 6)*64;
  #pragma unroll
  for(int fr = 0; fr < 4; ++fr)
    #pragma unroll
    for(int fc = 0; fc < 2; ++fc){
      int c = wc*32 + fc*16 + lrow;
      float bb0 = b0[c], bb1 = b1[c];
      #pragma unroll
      for(int q = 0; q < 4; ++q){
        int rl = fr*16 + lgrp*4 + q;
        float v = (acc[fr][fc][0][q] + bb0) * sigm(acc[fr][fc][1][q] + bb1);
        *(unsigned short*)(&lds[c*128 + ((rl*2) ^ ((c & 7) << 4))]) = f2bf(v);
      }
    }
  __syncthreads();
  {
    int d8 = lane >> 3, c8 = lane & 7;   // 8 lanes -> 128B contiguous per d
    #pragma unroll
    for(int t = 0; t < 4; ++t){
      int d = wid*32 + t*8 + d8;
      uint4 v = *(const uint4*)(&lds[d*128 + ((c8*16) ^ ((d & 7) << 4))]);
      *(uint4*)(dst + (long)d*MM + (long)j0*NN + k0 + c8*8) = v;
    }
  }
}

// ---------------------------------------------------------------------------
// k_einsum: per channel d: mid[d][i][j] = (1/384) * sum_k Rt[d][i][k]*Lt[d][j][k]
// 128x128 tile, K=384 in 6 k-tiles of 64, double-buffered global_load_lds
// staging, LDS-repacked coalesced output.
__global__ __launch_bounds__(256) void k_einsum(
    const unsigned short* __restrict__ Rt, const unsigned short* __restrict__ Lt,
    unsigned short* __restrict__ mid){
  __shared__ char lds[65536];            // 2 bufs x (A[128][128B] + B[128][128B])
  const int d = blockIdx.y;
  const int it = blockIdx.x / 3, jt = blockIdx.x % 3;
  const int i0 = it*128, j0 = jt*128;
  const unsigned short* Abase = Rt + (long)d*MM;
  const unsigned short* Bbase = Lt + (long)d*MM;
  const int wid = threadIdx.x >> 6, lane = threadIdx.x & 63;
  const int wr = wid >> 1, wc = wid & 1;
  const int lrow = lane & 15, lgrp = lane >> 4;

  auto stage = [&](int buf, int kt){
    int k = kt*64;
    int c = lane & 7;
    #pragma unroll
    for(int t = 0; t < 8; ++t){
      int rr = wid*64 + t*8 + (lane >> 3);   // 0..255 (first 128 = A rows)
      int r = rr & 127;
      const unsigned short* src = (rr < 128) ? (Abase + (long)(i0+r)*NN + k)
                                             : (Bbase + (long)(j0+r)*NN + k);
      gll16(src + (c ^ (r & 7))*8, &lds[buf*32768 + (wid*64 + t*8)*128]);
    }
  };

  f32x4 zero = {0.f,0.f,0.f,0.f};
  f32x4 acc[4][4];
  #pragma unroll
  for(int a1 = 0; a1 < 4; ++a1)
    #pragma unroll
    for(int a2 = 0; a2 < 4; ++a2) acc[a1][a2] = zero;

  stage(0, 0);
  __syncthreads();
  for(int kt = 0; kt < 6; ++kt){
    int cur = kt & 1;
    if(kt < 5) stage(cur ^ 1, kt + 1);   // prefetch flies during compute
    const int base = cur*32768;
    #pragma unroll
    for(int ks = 0; ks < 2; ++ks){
      short8 af[4], bf[4];
      #pragma unroll
      for(int f = 0; f < 4; ++f){
        int ra = wr*64 + f*16 + lrow;
        af[f] = *(const short8*)(&lds[base + ra*128 + (((ks*4+lgrp)*16) ^ ((ra & 7) << 4))]);
        int rb = wc*64 + f*16 + lrow;
        bf[f] = *(const short8*)(&lds[base + 16384 + rb*128 + (((ks*4+lgrp)*16) ^ ((rb & 7) << 4))]);
      }
      #pragma unroll
      for(int fr = 0; fr < 4; ++fr)
        #pragma unroll
        for(int fc = 0; fc < 4; ++fc)
          acc[fr][fc] = mfma16(af[fr], bf[fc], acc[fr][fc]);
    }
    __syncthreads();                     // drains prefetch vmcnt + buffer handoff
  }

  // repack to LDS (buf0) then coalesced 16B writes
  const float s = 1.0f/384.0f;
  #pragma unroll
  for(int fr = 0; fr < 4; ++fr)
    #pragma unroll
    for(int fc = 0; fc < 4; ++fc){
      int jl = wc*64 + fc*16 + lrow;
      #pragma unroll
      for(int q = 0; q < 4; ++q){
        int il = wr*64 + fr*16 + lgrp*4 + q;
        *(unsigned short*)(&lds[il*256 + ((jl*2) ^ ((il & 7) << 4))]) = f2bf(acc[fr][fc][q]*s);
      }
    }
  __syncthreads();
  {
    int i2 = lane >> 4, c16 = lane & 15;
    #pragma unroll
    for(int t = 0; t < 8; ++t){
      int il = wid*32 + t*4 + i2;
      uint4 v = *(const uint4*)(&lds[il*256 + ((c16*16) ^ ((il & 7) << 4))]);
      *(uint4*)(mid + (long)d*MM + (long)(i0+il)*NN + j0 + c16*8) = v;
    }
  }
}

// ---------------------------------------------------------------------------
// k_final: per (i, 32-wide j strip): gather mid[d][i][j], LN over d, *gate,
//          bf16 MFMA vs Wo^T, +bo, fp32 out.
__global__ __launch_bounds__(256) void k_final(
    const unsigned short* __restrict__ mid, const unsigned short* __restrict__ gate,
    const float* __restrict__ ona, const float* __restrict__ onb,
    const unsigned short* __restrict__ Wot, const float* __restrict__ bo,
    float* __restrict__ out){
  __shared__ float midt[32][129];
  __shared__ char vlds[8192];            // [32 j][128 d] bf16, swizzled
  const int i = blockIdx.y;
  const int j0 = blockIdx.x*32;

  { // gather mid: 4B per lane, 64B contiguous per d-plane
    int jp = threadIdx.x & 15, dr = threadIdx.x >> 4;
    #pragma unroll
    for(int pass = 0; pass < 8; ++pass){
      int dd = dr + pass*16;
      unsigned v = *(const unsigned*)(mid + (long)dd*MM + (long)i*NN + j0 + jp*2);
      midt[jp*2][dd]   = bf2f((unsigned short)(v & 0xffffu));
      midt[jp*2+1][dd] = bf2f((unsigned short)(v >> 16));
    }
  }
  __syncthreads();

  { // LN + gate, 8 threads per j-row
    int j = threadIdx.x >> 3, s = threadIdx.x & 7;
    float sum = 0.f, sq = 0.f;
    #pragma unroll
    for(int o = 0; o < 16; ++o){ float v = midt[j][s*16 + o]; sum += v; sq += v*v; }
    #pragma unroll
    for(int m = 1; m < 8; m <<= 1){ sum += __shfl_xor(sum, m); sq += __shfl_xor(sq, m); }
    float mean = sum*(1.f/128.f);
    float var  = sq *(1.f/128.f) - mean*mean;
    float rstd = rsqrtf(var + 1e-5f);
    long gr = ((long)i*NN + j0 + j)*DD;
    #pragma unroll
    for(int o = 0; o < 16; o += 2){
      int dd = s*16 + o;
      unsigned gv = *(const unsigned*)(gate + gr + dd);
      float g0 = bf2f((unsigned short)(gv & 0xffffu));
      float g1 = bf2f((unsigned short)(gv >> 16));
      float v0 = (ona[dd]  *(midt[j][dd]  -mean)*rstd + onb[dd]  )*g0;
      float v1 = (ona[dd+1]*(midt[j][dd+1]-mean)*rstd + onb[dd+1])*g1;
      unsigned pk = (unsigned)f2bf(v0) | ((unsigned)f2bf(v1) << 16);
      *(unsigned*)(&vlds[j*256 + ((dd*2) ^ ((j & 7) << 4))]) = pk;
    }
  }
  __syncthreads();

  const int wid = threadIdx.x >> 6, lane = threadIdx.x & 63;
  const int wr = wid >> 1, wc = wid & 1;
  const int lrow = lane & 15, lgrp = lane >> 4;
  f32x4 zero = {0.f,0.f,0.f,0.f};
  f32x4 acc[4] = {zero, zero, zero, zero};
  #pragma unroll
  for(int ks = 0; ks < 4; ++ks){
    int row = wr*16 + lrow;
    short8 a = *(const short8*)(&vlds[row*256 + (((ks*4+lgrp)*16) ^ ((row & 7) << 4))]);
    #pragma unroll
    for(int fc = 0; fc < 4; ++fc){
      int n = wc*64 + fc*16 + lrow;
      short8 b = *(const short8*)(Wot + n*128 + ks*32 + lgrp*8);
      acc[fc] = mfma16(a, b, acc[fc]);
    }
  }
  #pragma unroll
  for(int fc = 0; fc < 4; ++fc){
    int c = wc*64 + fc*16 + lrow;
    float bb = bo[c];
    #pragma unroll
    for(int q = 0; q < 4; ++q){
      int jl = wr*16 + lgrp*4 + q;
      out[((long)i*NN + j0 + jl)*DD + c] = acc[fc][q] + bb;
    }
  }
}

// ---------------------------------------------------------------------------
extern "C" void kernel_launch(void* const* d_in, const int* in_sizes, int n_in,
                              void* d_out, int out_size, void* d_ws, size_t ws_size,
                              hipStream_t stream){
  const float* x   = (const float*)d_in[0];
  const float* na  = (const float*)d_in[1];
  const float* nb  = (const float*)d_in[2];
  const float* Wl  = (const float*)d_in[3];
  const float* bl  = (const float*)d_in[4];
  const float* Wr  = (const float*)d_in[5];
  const float* br  = (const float*)d_in[6];
  const float* Wlg = (const float*)d_in[7];
  const float* blg = (const float*)d_in[8];
  const float* Wrg = (const float*)d_in[9];
  const float* brg = (const float*)d_in[10];
  const float* Wog = (const float*)d_in[11];
  const float* bog = (const float*)d_in[12];
  const float* ona = (const float*)d_in[13];
  const float* onb = (const float*)d_in[14];
  const float* Wo  = (const float*)d_in[15];
  const float* bo  = (const float*)d_in[16];
  float* out = (float*)d_out;

  char* ws = (char*)d_ws;
  const size_t SZ = (size_t)MM*DD*2;                    // 37.75 MB
  unsigned short* xn   = (unsigned short*)(ws);         // region0 (later: mid)
  unsigned short* Lt   = (unsigned short*)(ws + SZ);
  unsigned short* Rt   = (unsigned short*)(ws + 2*SZ);
  unsigned short* gate = (unsigned short*)(ws + 3*SZ);
  unsigned short* Wcat = (unsigned short*)(ws + 4*SZ);
  unsigned short* Wot  = (unsigned short*)(ws + 4*SZ + (size_t)640*128*2);
  unsigned short* mid  = xn;   // xn dead after k_proj; overlay

  k_prep  <<<768, 64, 0, stream>>>(Wl, Wlg, Wr, Wrg, Wog, Wo, Wcat, Wot);
  k_ln_x  <<<MM/4, 256, 0, stream>>>(x, na, nb, xn);
  k_proj  <<<dim3(2304, 3), 256, 0, stream>>>(xn, Wcat, bl, blg, br, brg, bog, Lt, Rt, gate);
  k_einsum<<<dim3(9, 128), 256, 0, stream>>>(Rt, Lt, mid);
  k_final <<<dim3(12, 384), 256, 0, stream>>>(mid, gate, ona, onb, Wot, bo, out);
}

// Round 3
// 211.296 us; speedup vs baseline: 1.2513x; 1.0429x over previous
//
#include <hip/hip_runtime.h>
#include <hip/hip_bf16.h>

#define NN 384
#define DD 128
#define MM (NN*NN)   // 147456 rows

typedef __attribute__((ext_vector_type(8))) short short8;
typedef __attribute__((ext_vector_type(4))) float f32x4;

__device__ __forceinline__ unsigned short f2bf(float f){
  unsigned u = __float_as_uint(f);
  u += 0x7fffu + ((u >> 16) & 1u);      // RNE
  return (unsigned short)(u >> 16);
}
__device__ __forceinline__ float bf2f(unsigned short u){
  return __uint_as_float(((unsigned)u) << 16);
}
__device__ __forceinline__ float sigm(float x){
  return 1.0f / (1.0f + __expf(-x));
}
__device__ __forceinline__ f32x4 mfma16(short8 a, short8 b, f32x4 c){
  return __builtin_amdgcn_mfma_f32_16x16x32_bf16(a, b, c, 0, 0, 0);
}
// async global->LDS, 16B/lane; LDS base wave-uniform (HW adds lane*16)
__device__ __forceinline__ void gll16(const void* g, void* l){
  __builtin_amdgcn_global_load_lds(
      (const __attribute__((address_space(1))) unsigned int*)g,
      (__attribute__((address_space(3))) unsigned int*)l, 16, 0, 0);
}

// ---------------------------------------------------------------------------
// k_prep: Wcat_t[n][k] bf16 = [Wl|Wlg|Wr|Wrg|Wog]^T (n in [0,640)); Wot = Wo^T.
__global__ void k_prep(const float* __restrict__ Wl, const float* __restrict__ Wlg,
                       const float* __restrict__ Wr, const float* __restrict__ Wrg,
                       const float* __restrict__ Wog, const float* __restrict__ Wo,
                       unsigned short* __restrict__ Wcat, unsigned short* __restrict__ Wot){
  int n = blockIdx.x;           // 0..767
  if(n < 640){
    const float* src; int col;
    if(n < 128){ src = Wl;  col = n; }
    else if(n < 256){ src = Wlg; col = n-128; }
    else if(n < 384){ src = Wr;  col = n-256; }
    else if(n < 512){ src = Wrg; col = n-384; }
    else            { src = Wog; col = n-512; }
    for(int k = threadIdx.x; k < 128; k += 64)
      Wcat[n*128 + k] = f2bf(src[k*128 + col]);
  } else {
    int c = n - 640;
    for(int k = threadIdx.x; k < 128; k += 64)
      Wot[c*128 + k] = f2bf(Wo[k*128 + c]);
  }
}

// ---------------------------------------------------------------------------
// k_ln_x: layernorm rows of x (fp32) -> xn bf16.  One wave per row.
__global__ __launch_bounds__(256) void k_ln_x(const float* __restrict__ x,
    const float* __restrict__ na, const float* __restrict__ nb,
    unsigned short* __restrict__ xn){
  int wid = threadIdx.x >> 6, lane = threadIdx.x & 63;
  long r = (long)blockIdx.x*4 + wid;
  float2 v = *(const float2*)(x + r*DD + lane*2);
  float s  = v.x + v.y;
  float sq = v.x*v.x + v.y*v.y;
  #pragma unroll
  for(int m = 32; m >= 1; m >>= 1){ s += __shfl_xor(s, m); sq += __shfl_xor(sq, m); }
  float mean = s  * (1.0f/128.0f);
  float var  = sq * (1.0f/128.0f) - mean*mean;
  float rstd = rsqrtf(var + 1e-5f);
  float2 a = *(const float2*)(na + lane*2);
  float2 b = *(const float2*)(nb + lane*2);
  unsigned pk = (unsigned)f2bf(a.x*(v.x-mean)*rstd + b.x)
              | ((unsigned)f2bf(a.y*(v.y-mean)*rstd + b.y) << 16);
  *(unsigned*)(xn + r*DD + lane*2) = pk;
}

// ---------------------------------------------------------------------------
// k_proj: 1-D grid 5760, 256 thr. XCD-grouped flavors.
//  LR blocks (slot<576): tile t (192 j-pairs x 6 k-64s), flavor f = d-quarter.
//    A tile: 128 rows (r = kk*2+jj -> xn[(k0+kk)*NN + j0+jj]), 32KB LDS.
//    B panel: 128 n (grp{L,Lg,R,Rg} x 32 d), 32KB LDS.
//    waves: ws = side (L/R), wr = 64-row half. Epilogue: gate-fuse + LDS
//    transpose -> Lt/Rt[d][j][k] in 128B-contiguous chunks.
//  gate blocks: 128 contiguous xn rows, Og proj, natural [m][d] out.
__global__ __launch_bounds__(256) void k_proj(
    const unsigned short* __restrict__ xn, const unsigned short* __restrict__ Wcat,
    const float* __restrict__ bl, const float* __restrict__ blg,
    const float* __restrict__ br, const float* __restrict__ brg,
    const float* __restrict__ bog,
    unsigned short* __restrict__ Lt, unsigned short* __restrict__ Rt,
    unsigned short* __restrict__ gate){
  __shared__ char lds[65536];            // [0,32K): A   [32K,64K): B
  const int tid = threadIdx.x;
  const int wid = tid >> 6, lane = tid & 63;
  const int lrow = lane & 15, lgrp = lane >> 4;
  const int b = blockIdx.x;
  const int xcd = b & 7, slot = b >> 3;  // 5760 = 8 * 720

  if(slot < 576){                        // ---------------- LR flavor
    const int t = (slot >> 2)*8 + xcd;   // 0..1151 tile
    const int f = slot & 3;              // d-quarter
    const int j0 = (t / 6)*2, k0 = (t % 6)*64;

    { // stage A: rows r = kk*2+jj, 4 rows / instr, pre-swizzled source
      int rsub = lane >> 4, c = lane & 15;
      #pragma unroll
      for(int p = 0; p < 8; ++p){
        int r0 = (wid*8 + p)*4;
        int r = r0 + rsub;
        long gr = (long)(k0 + (r >> 1))*NN + (j0 + (r & 1));
        gll16(xn + gr*DD + (c ^ (r & 7))*8, &lds[r0*256]);
      }
    }
    { // stage B: n_local = grp*32+i -> Wcat row grp*128 + f*32 + i
      int rsub = lane >> 4, c = lane & 15;
      #pragma unroll
      for(int p = 0; p < 8; ++p){
        int n0 = (wid*8 + p)*4;
        int nl = n0 + rsub;
        int ng = (nl >> 5)*128 + f*32 + (nl & 31);
        gll16(Wcat + ng*DD + (c ^ (nl & 7))*8, &lds[32768 + n0*256]);
      }
    }
    __syncthreads();

    const int ws = wid >> 1;             // 0=L 1=R
    const int wr = wid & 1;              // 64-row half
    f32x4 zero = {0.f,0.f,0.f,0.f};
    f32x4 acc[4][2][2];
    #pragma unroll
    for(int a1=0;a1<4;++a1)
      #pragma unroll
      for(int a2=0;a2<2;++a2)
        #pragma unroll
        for(int a3=0;a3<2;++a3) acc[a1][a2][a3] = zero;

    #pragma unroll 1
    for(int ks = 0; ks < 4; ++ks){
      short8 af[4];
      #pragma unroll
      for(int fr = 0; fr < 4; ++fr){
        int r = wr*64 + fr*16 + lrow;
        af[fr] = *(const short8*)(&lds[r*256 + (((ks*4+lgrp)*16) ^ ((r&7)<<4))]);
      }
      short8 bf[2][2];
      #pragma unroll
      for(int fc = 0; fc < 2; ++fc)
        #pragma unroll
        for(int p = 0; p < 2; ++p){
          int nl = (ws*2+p)*32 + fc*16 + lrow;
          bf[fc][p] = *(const short8*)(&lds[32768 + nl*256 + (((ks*4+lgrp)*16) ^ ((nl&7)<<4))]);
        }
      #pragma unroll
      for(int fr = 0; fr < 4; ++fr)
        #pragma unroll
        for(int fc = 0; fc < 2; ++fc){
          acc[fr][fc][0] = mfma16(af[fr], bf[fc][0], acc[fr][fc][0]);
          acc[fr][fc][1] = mfma16(af[fr], bf[fc][1], acc[fr][fc][1]);
        }
    }
    __syncthreads();                     // A/B dead; LDS reused

    // epilogue: gate-fuse, transpose buffer [side][32 d][128 pos] (pos = jj*64+kk)
    const float* b0 = ws ? br  : bl;
    const float* b1 = ws ? brg : blg;
    #pragma unroll
    for(int fr = 0; fr < 4; ++fr)
      #pragma unroll
      for(int fc = 0; fc < 2; ++fc){
        int dl = fc*16 + lrow;
        float bb0 = b0[f*32 + dl], bb1 = b1[f*32 + dl];
        #pragma unroll
        for(int q = 0; q < 4; ++q){
          int r = wr*64 + fr*16 + lgrp*4 + q;
          int pos = (r & 1)*64 + (r >> 1);             // (jj,kk)
          float v = (acc[fr][fc][0][q] + bb0) * sigm(acc[fr][fc][1][q] + bb1);
          *(unsigned short*)(&lds[ws*8192 + dl*256 + ((pos*2) ^ ((dl&7)<<4))]) = f2bf(v);
        }
      }
    __syncthreads();
    { // write-out: 128B chunk per (d,jj), 8 lanes each
      int c8 = tid & 7;
      #pragma unroll
      for(int t4 = 0; t4 < 4; ++t4){
        int chunk = t4*32 + (tid >> 3);  // 0..127
        int side = chunk >> 6, w = chunk & 63;
        int dl = w >> 1, jj = w & 1;
        uint4 v = *(const uint4*)(&lds[side*8192 + dl*256 + ((jj*128 + c8*16) ^ ((dl&7)<<4))]);
        unsigned short* dst = (side ? Rt : Lt) + (long)(f*32 + dl)*MM
                            + (long)(j0 + jj)*NN + k0 + c8*8;
        *(uint4*)dst = v;
      }
    }
  } else {                               // ---------------- gate flavor
    const int m = (slot - 576)*8 + xcd;  // 0..1151 (128-row tiles)
    { // stage A: contiguous rows
      int rsub = lane >> 4, c = lane & 15;
      #pragma unroll
      for(int p = 0; p < 8; ++p){
        int r0 = (wid*8 + p)*4;
        int r = r0 + rsub;
        long gr = (long)m*128 + r;
        gll16(xn + gr*DD + (c ^ (r & 7))*8, &lds[r0*256]);
      }
    }
    { // stage B: Og rows 512..639
      int rsub = lane >> 4, c = lane & 15;
      #pragma unroll
      for(int p = 0; p < 8; ++p){
        int n0 = (wid*8 + p)*4;
        int nl = n0 + rsub;
        gll16(Wcat + (512 + nl)*DD + (c ^ (nl & 7))*8, &lds[32768 + n0*256]);
      }
    }
    __syncthreads();

    f32x4 zero = {0.f,0.f,0.f,0.f};
    f32x4 acc[2][8];
    #pragma unroll
    for(int a1=0;a1<2;++a1)
      #pragma unroll
      for(int a2=0;a2<8;++a2) acc[a1][a2] = zero;

    #pragma unroll 1
    for(int ks = 0; ks < 4; ++ks){
      short8 af[2];
      #pragma unroll
      for(int fr = 0; fr < 2; ++fr){
        int r = wid*32 + fr*16 + lrow;
        af[fr] = *(const short8*)(&lds[r*256 + (((ks*4+lgrp)*16) ^ ((r&7)<<4))]);
      }
      #pragma unroll
      for(int fc = 0; fc < 8; ++fc){
        int nl = fc*16 + lrow;
        short8 bf = *(const short8*)(&lds[32768 + nl*256 + (((ks*4+lgrp)*16) ^ ((nl&7)<<4))]);
        acc[0][fc] = mfma16(af[0], bf, acc[0][fc]);
        acc[1][fc] = mfma16(af[1], bf, acc[1][fc]);
      }
    }
    __syncthreads();

    #pragma unroll
    for(int fr = 0; fr < 2; ++fr)
      #pragma unroll
      for(int fc = 0; fc < 8; ++fc){
        int c = fc*16 + lrow;
        float bias = bog[c];
        #pragma unroll
        for(int q = 0; q < 4; ++q){
          int r = wid*32 + fr*16 + lgrp*4 + q;
          *(unsigned short*)(&lds[r*256 + ((c*2) ^ ((r&7)<<4))])
              = f2bf(sigm(acc[fr][fc][q] + bias));
        }
      }
    __syncthreads();
    {
      int c16 = tid & 15;
      #pragma unroll
      for(int p = 0; p < 8; ++p){
        int row = p*16 + (tid >> 4);
        uint4 v = *(const uint4*)(&lds[row*256 + ((c16*16) ^ ((row&7)<<4))]);
        *(uint4*)(gate + ((long)m*128 + row)*DD + c16*8) = v;
      }
    }
  }
}

// ---------------------------------------------------------------------------
// k_einsum: per channel d: mid[d][i][j] = (1/384) sum_k Rt[d][i][k]*Lt[d][j][k]
// 128x128 tile, double-buffered gll16 staging; same-d blocks XCD-grouped.
__global__ __launch_bounds__(256) void k_einsum(
    const unsigned short* __restrict__ Rt, const unsigned short* __restrict__ Lt,
    unsigned short* __restrict__ mid){
  __shared__ char lds[65536];            // 2 bufs x (A[128][128B] + B[128][128B])
  const int b = blockIdx.x;              // 1152 = 8 * 144
  const int xcd = b & 7, slot = b >> 3;
  const int d = (slot/9)*8 + xcd;        // same-d blocks share an XCD
  const int t = slot % 9;
  const int it = t/3, jt = t%3;
  const int i0 = it*128, j0 = jt*128;
  const unsigned short* Abase = Rt + (long)d*MM;
  const unsigned short* Bbase = Lt + (long)d*MM;
  const int wid = threadIdx.x >> 6, lane = threadIdx.x & 63;
  const int wr = wid >> 1, wc = wid & 1;
  const int lrow = lane & 15, lgrp = lane >> 4;

  auto stage = [&](int buf, int kt){
    int k = kt*64;
    int c = lane & 7;
    #pragma unroll
    for(int t8 = 0; t8 < 8; ++t8){
      int rr = wid*64 + t8*8 + (lane >> 3);   // 0..255 (first 128 = A rows)
      int r = rr & 127;
      const unsigned short* src = (rr < 128) ? (Abase + (long)(i0+r)*NN + k)
                                             : (Bbase + (long)(j0+r)*NN + k);
      gll16(src + (c ^ (r & 7))*8, &lds[buf*32768 + (wid*64 + t8*8)*128]);
    }
  };

  f32x4 zero = {0.f,0.f,0.f,0.f};
  f32x4 acc[4][4];
  #pragma unroll
  for(int a1 = 0; a1 < 4; ++a1)
    #pragma unroll
    for(int a2 = 0; a2 < 4; ++a2) acc[a1][a2] = zero;

  stage(0, 0);
  __syncthreads();
  for(int kt = 0; kt < 6; ++kt){
    int cur = kt & 1;
    if(kt < 5) stage(cur ^ 1, kt + 1);
    const int base = cur*32768;
    #pragma unroll
    for(int ks = 0; ks < 2; ++ks){
      short8 af[4], bf[4];
      #pragma unroll
      for(int f = 0; f < 4; ++f){
        int ra = wr*64 + f*16 + lrow;
        af[f] = *(const short8*)(&lds[base + ra*128 + (((ks*4+lgrp)*16) ^ ((ra & 7) << 4))]);
        int rb = wc*64 + f*16 + lrow;
        bf[f] = *(const short8*)(&lds[base + 16384 + rb*128 + (((ks*4+lgrp)*16) ^ ((rb & 7) << 4))]);
      }
      #pragma unroll
      for(int fr = 0; fr < 4; ++fr)
        #pragma unroll
        for(int fc = 0; fc < 4; ++fc)
          acc[fr][fc] = mfma16(af[fr], bf[fc], acc[fr][fc]);
    }
    __syncthreads();
  }

  const float s = 1.0f/384.0f;
  #pragma unroll
  for(int fr = 0; fr < 4; ++fr)
    #pragma unroll
    for(int fc = 0; fc < 4; ++fc){
      int jl = wc*64 + fc*16 + lrow;
      #pragma unroll
      for(int q = 0; q < 4; ++q){
        int il = wr*64 + fr*16 + lgrp*4 + q;
        *(unsigned short*)(&lds[il*256 + ((jl*2) ^ ((il & 7) << 4))]) = f2bf(acc[fr][fc][q]*s);
      }
    }
  __syncthreads();
  {
    int i2 = lane >> 4, c16 = lane & 15;
    #pragma unroll
    for(int t8 = 0; t8 < 8; ++t8){
      int il = wid*32 + t8*4 + i2;
      uint4 v = *(const uint4*)(&lds[il*256 + ((c16*16) ^ ((il & 7) << 4))]);
      *(uint4*)(mid + (long)d*MM + (long)(i0+il)*NN + j0 + c16*8) = v;
    }
  }
}

// ---------------------------------------------------------------------------
// k_final: per (i, 64-wide j strip): gather mid[d][i][j] (128B chunks),
//          LN over d, *gate, bf16 MFMA vs Wo^T, +bo, fp32 out.
__global__ __launch_bounds__(256) void k_final(
    const unsigned short* __restrict__ mid, const unsigned short* __restrict__ gate,
    const float* __restrict__ ona, const float* __restrict__ onb,
    const unsigned short* __restrict__ Wot, const float* __restrict__ bo,
    float* __restrict__ out){
  __shared__ float midt[64][129];
  __shared__ char vlds[16384];           // [64 j][128 d] bf16, swizzled
  const int tid = threadIdx.x;
  const int i = blockIdx.y;
  const int j0 = blockIdx.x*64;

  { // gather: uint2 = 4 consecutive j, 16 lanes = 128B per (i,d)
    int jp = tid & 15, dr = tid >> 4;
    #pragma unroll
    for(int pass = 0; pass < 8; ++pass){
      int dd = pass*16 + dr;
      uint2 v = *(const uint2*)(mid + (long)dd*MM + (long)i*NN + j0 + jp*4);
      midt[jp*4+0][dd] = bf2f((unsigned short)(v.x & 0xffffu));
      midt[jp*4+1][dd] = bf2f((unsigned short)(v.x >> 16));
      midt[jp*4+2][dd] = bf2f((unsigned short)(v.y & 0xffffu));
      midt[jp*4+3][dd] = bf2f((unsigned short)(v.y >> 16));
    }
  }
  __syncthreads();

  { // LN + gate, 4 threads per j-row (32 d each)
    int j = tid >> 2, s = tid & 3;
    float sum = 0.f, sq = 0.f;
    #pragma unroll
    for(int o = 0; o < 32; ++o){ float v = midt[j][s*32 + o]; sum += v; sq += v*v; }
    #pragma unroll
    for(int m = 1; m < 4; m <<= 1){ sum += __shfl_xor(sum, m); sq += __shfl_xor(sq, m); }
    float mean = sum*(1.f/128.f);
    float var  = sq *(1.f/128.f) - mean*mean;
    float rstd = rsqrtf(var + 1e-5f);
    long gr = ((long)i*NN + j0 + j)*DD;
    #pragma unroll
    for(int o = 0; o < 32; o += 4){
      int dd = s*32 + o;
      uint2 gv = *(const uint2*)(gate + gr + dd);
      float g0 = bf2f((unsigned short)(gv.x & 0xffffu));
      float g1 = bf2f((unsigned short)(gv.x >> 16));
      float g2 = bf2f((unsigned short)(gv.y & 0xffffu));
      float g3 = bf2f((unsigned short)(gv.y >> 16));
      float v0 = (ona[dd]  *(midt[j][dd]  -mean)*rstd + onb[dd]  )*g0;
      float v1 = (ona[dd+1]*(midt[j][dd+1]-mean)*rstd + onb[dd+1])*g1;
      float v2 = (ona[dd+2]*(midt[j][dd+2]-mean)*rstd + onb[dd+2])*g2;
      float v3 = (ona[dd+3]*(midt[j][dd+3]-mean)*rstd + onb[dd+3])*g3;
      unsigned pk01 = (unsigned)f2bf(v0) | ((unsigned)f2bf(v1) << 16);
      unsigned pk23 = (unsigned)f2bf(v2) | ((unsigned)f2bf(v3) << 16);
      *(unsigned*)(&vlds[j*256 + ((dd*2)     ^ ((j & 7) << 4))]) = pk01;
      *(unsigned*)(&vlds[j*256 + ((dd*2 + 4) ^ ((j & 7) << 4))]) = pk23;
    }
  }
  __syncthreads();

  const int wid = tid >> 6, lane = tid & 63;
  const int lrow = lane & 15, lgrp = lane >> 4;
  f32x4 zero = {0.f,0.f,0.f,0.f};
  f32x4 acc[8];
  #pragma unroll
  for(int fc = 0; fc < 8; ++fc) acc[fc] = zero;
  #pragma unroll 1
  for(int ks = 0; ks < 4; ++ks){
    int row = wid*16 + lrow;
    short8 a = *(const short8*)(&vlds[row*256 + (((ks*4+lgrp)*16) ^ ((row & 7) << 4))]);
    #pragma unroll
    for(int fc = 0; fc < 8; ++fc){
      int n = fc*16 + lrow;
      short8 bfr = *(const short8*)(Wot + n*128 + ks*32 + lgrp*8);
      acc[fc] = mfma16(a, bfr, acc[fc]);
    }
  }
  #pragma unroll
  for(int fc = 0; fc < 8; ++fc){
    int c = fc*16 + lrow;
    float bb = bo[c];
    #pragma unroll
    for(int q = 0; q < 4; ++q){
      int jl = wid*16 + lgrp*4 + q;
      out[((long)i*NN + j0 + jl)*DD + c] = acc[fc][q] + bb;
    }
  }
}

// ---------------------------------------------------------------------------
extern "C" void kernel_launch(void* const* d_in, const int* in_sizes, int n_in,
                              void* d_out, int out_size, void* d_ws, size_t ws_size,
                              hipStream_t stream){
  const float* x   = (const float*)d_in[0];
  const float* na  = (const float*)d_in[1];
  const float* nb  = (const float*)d_in[2];
  const float* Wl  = (const float*)d_in[3];
  const float* bl  = (const float*)d_in[4];
  const float* Wr  = (const float*)d_in[5];
  const float* br  = (const float*)d_in[6];
  const float* Wlg = (const float*)d_in[7];
  const float* blg = (const float*)d_in[8];
  const float* Wrg = (const float*)d_in[9];
  const float* brg = (const float*)d_in[10];
  const float* Wog = (const float*)d_in[11];
  const float* bog = (const float*)d_in[12];
  const float* ona = (const float*)d_in[13];
  const float* onb = (const float*)d_in[14];
  const float* Wo  = (const float*)d_in[15];
  const float* bo  = (const float*)d_in[16];
  float* out = (float*)d_out;

  char* ws = (char*)d_ws;
  const size_t SZ = (size_t)MM*DD*2;                    // 37.75 MB
  unsigned short* xn   = (unsigned short*)(ws);         // region0 (later: mid)
  unsigned short* Lt   = (unsigned short*)(ws + SZ);
  unsigned short* Rt   = (unsigned short*)(ws + 2*SZ);
  unsigned short* gate = (unsigned short*)(ws + 3*SZ);
  unsigned short* Wcat = (unsigned short*)(ws + 4*SZ);
  unsigned short* Wot  = (unsigned short*)(ws + 4*SZ + (size_t)640*128*2);
  unsigned short* mid  = xn;   // xn dead after k_proj; overlay

  k_prep  <<<768, 64, 0, stream>>>(Wl, Wlg, Wr, Wrg, Wog, Wo, Wcat, Wot);
  k_ln_x  <<<MM/4, 256, 0, stream>>>(x, na, nb, xn);
  k_proj  <<<5760, 256, 0, stream>>>(xn, Wcat, bl, blg, br, brg, bog, Lt, Rt, gate);
  k_einsum<<<1152, 256, 0, stream>>>(Rt, Lt, mid);
  k_final <<<dim3(6, 384), 256, 0, stream>>>(mid, gate, ona, onb, Wot, bo, out);
}

// Round 4
// 200.323 us; speedup vs baseline: 1.3199x; 1.0548x over previous
//
#include <hip/hip_runtime.h>
#include <hip/hip_bf16.h>

#define NN 384
#define DD 128
#define MM (NN*NN)   // 147456 rows

typedef __attribute__((ext_vector_type(8))) short short8;
typedef __attribute__((ext_vector_type(4))) float f32x4;

__device__ __forceinline__ unsigned short f2bf(float f){
  unsigned u = __float_as_uint(f);
  u += 0x7fffu + ((u >> 16) & 1u);      // RNE
  return (unsigned short)(u >> 16);
}
__device__ __forceinline__ float bf2f(unsigned short u){
  return __uint_as_float(((unsigned)u) << 16);
}
__device__ __forceinline__ float sigm(float x){
  return 1.0f / (1.0f + __expf(-x));
}
__device__ __forceinline__ unsigned cvtpk(float lo, float hi){
  unsigned r;
  asm("v_cvt_pk_bf16_f32 %0, %1, %2" : "=v"(r) : "v"(lo), "v"(hi));
  return r;
}
__device__ __forceinline__ f32x4 mfma16(short8 a, short8 b, f32x4 c){
  return __builtin_amdgcn_mfma_f32_16x16x32_bf16(a, b, c, 0, 0, 0);
}
// async global->LDS, 16B/lane; LDS base wave-uniform (HW adds lane*16)
__device__ __forceinline__ void gll16(const void* g, void* l){
  __builtin_amdgcn_global_load_lds(
      (const __attribute__((address_space(1))) unsigned int*)g,
      (__attribute__((address_space(3))) unsigned int*)l, 16, 0, 0);
}

// ---------------------------------------------------------------------------
// k_prep: Wcat_t[n][k] bf16 = [Wl|Wlg|Wr|Wrg|Wog]^T (n in [0,640)); Wot = Wo^T.
__global__ void k_prep(const float* __restrict__ Wl, const float* __restrict__ Wlg,
                       const float* __restrict__ Wr, const float* __restrict__ Wrg,
                       const float* __restrict__ Wog, const float* __restrict__ Wo,
                       unsigned short* __restrict__ Wcat, unsigned short* __restrict__ Wot){
  int n = blockIdx.x;           // 0..767
  if(n < 640){
    const float* src; int col;
    if(n < 128){ src = Wl;  col = n; }
    else if(n < 256){ src = Wlg; col = n-128; }
    else if(n < 384){ src = Wr;  col = n-256; }
    else if(n < 512){ src = Wrg; col = n-384; }
    else            { src = Wog; col = n-512; }
    for(int k = threadIdx.x; k < 128; k += 64)
      Wcat[n*128 + k] = f2bf(src[k*128 + col]);
  } else {
    int c = n - 640;
    for(int k = threadIdx.x; k < 128; k += 64)
      Wot[c*128 + k] = f2bf(Wo[k*128 + c]);
  }
}

// ---------------------------------------------------------------------------
// k_ln_x: layernorm rows of x (fp32) -> xn bf16.  One wave per row.
__global__ __launch_bounds__(256) void k_ln_x(const float* __restrict__ x,
    const float* __restrict__ na, const float* __restrict__ nb,
    unsigned short* __restrict__ xn){
  int wid = threadIdx.x >> 6, lane = threadIdx.x & 63;
  long r = (long)blockIdx.x*4 + wid;
  float2 v = *(const float2*)(x + r*DD + lane*2);
  float s  = v.x + v.y;
  float sq = v.x*v.x + v.y*v.y;
  #pragma unroll
  for(int m = 32; m >= 1; m >>= 1){ s += __shfl_xor(s, m); sq += __shfl_xor(sq, m); }
  float mean = s  * (1.0f/128.0f);
  float var  = sq * (1.0f/128.0f) - mean*mean;
  float rstd = rsqrtf(var + 1e-5f);
  float2 a = *(const float2*)(na + lane*2);
  float2 b = *(const float2*)(nb + lane*2);
  unsigned pk = (unsigned)f2bf(a.x*(v.x-mean)*rstd + b.x)
              | ((unsigned)f2bf(a.y*(v.y-mean)*rstd + b.y) << 16);
  *(unsigned*)(xn + r*DD + lane*2) = pk;
}

// ---------------------------------------------------------------------------
// k_proj: 512 thr (8 waves), 1-D grid 5760, XCD-grouped.
//  LR (slot<576): tile t, flavor f (d-quarter). A-tile rows r = jj*64+kk ->
//    xn[(k0+kk)*NN + j0+jj] (32KB). B: flavor's 128 n (4 types x 32 d, 32KB).
//    Wave (ws=side, wd=d-half, wr=jj). Thread's acc q-run = consecutive kk ->
//    packed 8B stores direct to Lt/Rt[d][j][k]. 1/384 folded into Lt.
//  gate (slot>=576): swapped operands (A=Wog^T, B=xn rows) -> acc q-run =
//    consecutive c -> packed 8B stores to gate[m][c].
__global__ __launch_bounds__(512, 4) void k_proj(
    const unsigned short* __restrict__ xn, const unsigned short* __restrict__ Wcat,
    const float* __restrict__ bl, const float* __restrict__ blg,
    const float* __restrict__ br, const float* __restrict__ brg,
    const float* __restrict__ bog,
    unsigned short* __restrict__ Lt, unsigned short* __restrict__ Rt,
    unsigned short* __restrict__ gate){
  __shared__ char lds[65536];            // [0,32K): xn tile   [32K,64K): W panel
  const int tid = threadIdx.x;
  const int wid = tid >> 6, lane = tid & 63;
  const int lrow = lane & 15, lgrp = lane >> 4;
  const int b = blockIdx.x;
  const int xcd = b & 7, slot = b >> 3;  // 5760 = 8 * 720

  if(slot < 576){                        // ---------------- LR flavor
    const int t = (slot >> 2)*8 + xcd;   // 0..1151 tile
    const int f = slot & 3;              // d-quarter
    const int j0 = (t / 6)*2, k0 = (t % 6)*64;

    { // stage A: 4 rows per gll16, r = jj*64+kk, pre-swizzled source
      int rsub = lane >> 4, c = lane & 15;
      #pragma unroll
      for(int p = 0; p < 4; ++p){
        int r0 = wid*16 + p*4;
        int r = r0 + rsub;
        long gr = (long)(k0 + (r & 63))*NN + (j0 + (r >> 6));
        gll16(xn + gr*DD + (c ^ (r & 7))*8, &lds[r0*256]);
      }
      // stage B: nl -> Wcat row (nl>>5)*128 + f*32 + (nl&31)
      #pragma unroll
      for(int p = 0; p < 4; ++p){
        int n0 = wid*16 + p*4;
        int nl = n0 + rsub;
        int ng = (nl >> 5)*128 + f*32 + (nl & 31);
        gll16(Wcat + ng*DD + (c ^ (nl & 7))*8, &lds[32768 + n0*256]);
      }
    }
    __syncthreads();

    const int ws = wid >> 2;             // 0=L 1=R
    const int wd = (wid >> 1) & 1;       // d-half of quarter
    const int wr = wid & 1;              // jj
    f32x4 zero = {0.f,0.f,0.f,0.f};
    f32x4 acc[4][2];
    #pragma unroll
    for(int a1=0;a1<4;++a1){ acc[a1][0] = zero; acc[a1][1] = zero; }

    #pragma unroll 2
    for(int ks = 0; ks < 4; ++ks){
      int nlv = ws*64 + wd*16 + lrow;    // val row in B panel
      short8 bv = *(const short8*)(&lds[32768 + nlv*256 + (((ks*4+lgrp)*16) ^ ((nlv&7)<<4))]);
      int nlg = nlv + 32;                // gate row
      short8 bg = *(const short8*)(&lds[32768 + nlg*256 + (((ks*4+lgrp)*16) ^ ((nlg&7)<<4))]);
      #pragma unroll
      for(int fr = 0; fr < 4; ++fr){
        int r = wr*64 + fr*16 + lrow;
        short8 af = *(const short8*)(&lds[r*256 + (((ks*4+lgrp)*16) ^ ((r&7)<<4))]);
        acc[fr][0] = mfma16(af, bv, acc[fr][0]);
        acc[fr][1] = mfma16(af, bg, acc[fr][1]);
      }
    }

    // epilogue: direct packed stores, no LDS
    const int d = f*32 + wd*16 + lrow;
    const float b0v = (ws ? br  : bl )[d];
    const float b1v = (ws ? brg : blg)[d];
    const float sc = ws ? 1.0f : (1.0f/384.0f);     // fold einsum 1/n into Lt
    unsigned short* dst = (ws ? Rt : Lt) + (long)d*MM + (long)(j0 + wr)*NN + k0;
    #pragma unroll
    for(int fr = 0; fr < 4; ++fr){
      float v0 = (acc[fr][0][0] + b0v)*sigm(acc[fr][1][0] + b1v)*sc;
      float v1 = (acc[fr][0][1] + b0v)*sigm(acc[fr][1][1] + b1v)*sc;
      float v2 = (acc[fr][0][2] + b0v)*sigm(acc[fr][1][2] + b1v)*sc;
      float v3 = (acc[fr][0][3] + b0v)*sigm(acc[fr][1][3] + b1v)*sc;
      uint2 pk; pk.x = cvtpk(v0, v1); pk.y = cvtpk(v2, v3);
      *(uint2*)(dst + fr*16 + lgrp*4) = pk;
    }
  } else {                               // ---------------- gate flavor
    const int m = (slot - 576)*8 + xcd;  // 0..1151 (128-row tiles)
    { // stage A: contiguous xn rows; B: Wog rows 512..639
      int rsub = lane >> 4, c = lane & 15;
      #pragma unroll
      for(int p = 0; p < 4; ++p){
        int r0 = wid*16 + p*4;
        int r = r0 + rsub;
        long gr = (long)m*128 + r;
        gll16(xn + gr*DD + (c ^ (r & 7))*8, &lds[r0*256]);
      }
      #pragma unroll
      for(int p = 0; p < 4; ++p){
        int n0 = wid*16 + p*4;
        int nl = n0 + rsub;
        gll16(Wcat + (512 + nl)*DD + (c ^ (nl & 7))*8, &lds[32768 + n0*256]);
      }
    }
    __syncthreads();

    const int wm = wid >> 2;             // m-row half (64 rows)
    const int wc = wid & 3;              // 32 c-cols
    f32x4 zero = {0.f,0.f,0.f,0.f};
    f32x4 acc[2][4];                     // [cf][mf]
    #pragma unroll
    for(int a1=0;a1<2;++a1)
      #pragma unroll
      for(int a2=0;a2<4;++a2) acc[a1][a2] = zero;

    #pragma unroll 2
    for(int ks = 0; ks < 4; ++ks){
      short8 af[2];
      #pragma unroll
      for(int cf = 0; cf < 2; ++cf){
        int nl = wc*32 + cf*16 + lrow;
        af[cf] = *(const short8*)(&lds[32768 + nl*256 + (((ks*4+lgrp)*16) ^ ((nl&7)<<4))]);
      }
      #pragma unroll
      for(int mf = 0; mf < 4; ++mf){
        int r = wm*64 + mf*16 + lrow;
        short8 bfr = *(const short8*)(&lds[r*256 + (((ks*4+lgrp)*16) ^ ((r&7)<<4))]);
        acc[0][mf] = mfma16(af[0], bfr, acc[0][mf]);
        acc[1][mf] = mfma16(af[1], bfr, acc[1][mf]);
      }
    }

    #pragma unroll
    for(int cf = 0; cf < 2; ++cf){
      int c = wc*32 + cf*16 + lgrp*4;
      float4 bo4 = *(const float4*)(bog + c);
      #pragma unroll
      for(int mf = 0; mf < 4; ++mf){
        int rr = wm*64 + mf*16 + lrow;
        float v0 = sigm(acc[cf][mf][0] + bo4.x);
        float v1 = sigm(acc[cf][mf][1] + bo4.y);
        float v2 = sigm(acc[cf][mf][2] + bo4.z);
        float v3 = sigm(acc[cf][mf][3] + bo4.w);
        uint2 pk; pk.x = cvtpk(v0, v1); pk.y = cvtpk(v2, v3);
        *(uint2*)(gate + ((long)m*128 + rr)*DD + c) = pk;
      }
    }
  }
}

// ---------------------------------------------------------------------------
// k_einsum: per d: mid[d][i][j] = sum_k Rt[d][i][k]*Lt[d][j][k]  (1/384 already
// folded into Lt).  A-operand = Lt j-rows, B-operand = Rt i-rows, so thread's
// acc q-run = consecutive j -> packed 8B direct stores.  Double-buffered gll16.
__global__ __launch_bounds__(256) void k_einsum(
    const unsigned short* __restrict__ Rt, const unsigned short* __restrict__ Lt,
    unsigned short* __restrict__ mid){
  __shared__ char lds[65536];            // 2 bufs x (A(Lt)[128][128B] + B(Rt)[128][128B])
  const int b = blockIdx.x;              // 1152 = 8 * 144
  const int xcd = b & 7, slot = b >> 3;
  const int d = (slot/9)*8 + xcd;        // same-d blocks share an XCD
  const int t = slot % 9;
  const int it = t/3, jt = t%3;
  const int i0 = it*128, j0 = jt*128;
  const unsigned short* Abase = Lt + (long)d*MM;   // j-rows
  const unsigned short* Bbase = Rt + (long)d*MM;   // i-rows
  const int wid = threadIdx.x >> 6, lane = threadIdx.x & 63;
  const int wr = wid >> 1, wc = wid & 1;
  const int lrow = lane & 15, lgrp = lane >> 4;

  auto stage = [&](int buf, int kt){
    int k = kt*64;
    int c = lane & 7;
    #pragma unroll
    for(int t8 = 0; t8 < 8; ++t8){
      int rr = wid*64 + t8*8 + (lane >> 3);   // 0..255 (first 128 = A rows)
      int r = rr & 127;
      const unsigned short* src = (rr < 128) ? (Abase + (long)(j0+r)*NN + k)
                                             : (Bbase + (long)(i0+r)*NN + k);
      gll16(src + (c ^ (r & 7))*8, &lds[buf*32768 + (wid*64 + t8*8)*128]);
    }
  };

  f32x4 zero = {0.f,0.f,0.f,0.f};
  f32x4 acc[4][4];                       // [fj][fi]
  #pragma unroll
  for(int a1 = 0; a1 < 4; ++a1)
    #pragma unroll
    for(int a2 = 0; a2 < 4; ++a2) acc[a1][a2] = zero;

  stage(0, 0);
  __syncthreads();
  for(int kt = 0; kt < 6; ++kt){
    int cur = kt & 1;
    if(kt < 5) stage(cur ^ 1, kt + 1);
    const int base = cur*32768;
    #pragma unroll
    for(int ks = 0; ks < 2; ++ks){
      short8 af[4], bf[4];
      #pragma unroll
      for(int f = 0; f < 4; ++f){
        int rj = wr*64 + f*16 + lrow;
        af[f] = *(const short8*)(&lds[base + rj*128 + (((ks*4+lgrp)*16) ^ ((rj & 7) << 4))]);
        int ri = wc*64 + f*16 + lrow;
        bf[f] = *(const short8*)(&lds[base + 16384 + ri*128 + (((ks*4+lgrp)*16) ^ ((ri & 7) << 4))]);
      }
      #pragma unroll
      for(int fj = 0; fj < 4; ++fj)
        #pragma unroll
        for(int fi = 0; fi < 4; ++fi)
          acc[fj][fi] = mfma16(af[fj], bf[fi], acc[fj][fi]);
    }
    __syncthreads();
  }

  // direct packed stores: thread holds mid[d][i][j..j+3]
  #pragma unroll
  for(int fj = 0; fj < 4; ++fj){
    int j = j0 + wr*64 + fj*16 + lgrp*4;
    #pragma unroll
    for(int fi = 0; fi < 4; ++fi){
      int i = i0 + wc*64 + fi*16 + lrow;
      uint2 pk;
      pk.x = cvtpk(acc[fj][fi][0], acc[fj][fi][1]);
      pk.y = cvtpk(acc[fj][fi][2], acc[fj][fi][3]);
      *(uint2*)(mid + (long)d*MM + (long)i*NN + j) = pk;
    }
  }
}

// ---------------------------------------------------------------------------
// k_final: per (i, 64-wide j strip): gather mid[d][i][j] (128B chunks),
//          LN over d, *gate, bf16 MFMA vs Wo^T, +bo, fp32 out.
__global__ __launch_bounds__(256) void k_final(
    const unsigned short* __restrict__ mid, const unsigned short* __restrict__ gate,
    const float* __restrict__ ona, const float* __restrict__ onb,
    const unsigned short* __restrict__ Wot, const float* __restrict__ bo,
    float* __restrict__ out){
  __shared__ float midt[64][129];
  __shared__ char vlds[16384];           // [64 j][128 d] bf16, swizzled
  const int tid = threadIdx.x;
  const int i = blockIdx.y;
  const int j0 = blockIdx.x*64;

  { // gather: uint2 = 4 consecutive j, 16 lanes = 128B per (i,d)
    int jp = tid & 15, dr = tid >> 4;
    #pragma unroll
    for(int pass = 0; pass < 8; ++pass){
      int dd = pass*16 + dr;
      uint2 v = *(const uint2*)(mid + (long)dd*MM + (long)i*NN + j0 + jp*4);
      midt[jp*4+0][dd] = bf2f((unsigned short)(v.x & 0xffffu));
      midt[jp*4+1][dd] = bf2f((unsigned short)(v.x >> 16));
      midt[jp*4+2][dd] = bf2f((unsigned short)(v.y & 0xffffu));
      midt[jp*4+3][dd] = bf2f((unsigned short)(v.y >> 16));
    }
  }
  __syncthreads();

  { // LN + gate, 4 threads per j-row (32 d each)
    int j = tid >> 2, s = tid & 3;
    float sum = 0.f, sq = 0.f;
    #pragma unroll
    for(int o = 0; o < 32; ++o){ float v = midt[j][s*32 + o]; sum += v; sq += v*v; }
    #pragma unroll
    for(int m = 1; m < 4; m <<= 1){ sum += __shfl_xor(sum, m); sq += __shfl_xor(sq, m); }
    float mean = sum*(1.f/128.f);
    float var  = sq *(1.f/128.f) - mean*mean;
    float rstd = rsqrtf(var + 1e-5f);
    long gr = ((long)i*NN + j0 + j)*DD;
    #pragma unroll
    for(int o = 0; o < 32; o += 4){
      int dd = s*32 + o;
      uint2 gv = *(const uint2*)(gate + gr + dd);
      float g0 = bf2f((unsigned short)(gv.x & 0xffffu));
      float g1 = bf2f((unsigned short)(gv.x >> 16));
      float g2 = bf2f((unsigned short)(gv.y & 0xffffu));
      float g3 = bf2f((unsigned short)(gv.y >> 16));
      float v0 = (ona[dd]  *(midt[j][dd]  -mean)*rstd + onb[dd]  )*g0;
      float v1 = (ona[dd+1]*(midt[j][dd+1]-mean)*rstd + onb[dd+1])*g1;
      float v2 = (ona[dd+2]*(midt[j][dd+2]-mean)*rstd + onb[dd+2])*g2;
      float v3 = (ona[dd+3]*(midt[j][dd+3]-mean)*rstd + onb[dd+3])*g3;
      unsigned pk01 = cvtpk(v0, v1);
      unsigned pk23 = cvtpk(v2, v3);
      *(unsigned*)(&vlds[j*256 + ((dd*2)     ^ ((j & 7) << 4))]) = pk01;
      *(unsigned*)(&vlds[j*256 + ((dd*2 + 4) ^ ((j & 7) << 4))]) = pk23;
    }
  }
  __syncthreads();

  const int wid = tid >> 6, lane = tid & 63;
  const int lrow = lane & 15, lgrp = lane >> 4;
  f32x4 zero = {0.f,0.f,0.f,0.f};
  f32x4 acc[8];
  #pragma unroll
  for(int fc = 0; fc < 8; ++fc) acc[fc] = zero;
  #pragma unroll 1
  for(int ks = 0; ks < 4; ++ks){
    int row = wid*16 + lrow;
    short8 a = *(const short8*)(&vlds[row*256 + (((ks*4+lgrp)*16) ^ ((row & 7) << 4))]);
    #pragma unroll
    for(int fc = 0; fc < 8; ++fc){
      int n = fc*16 + lrow;
      short8 bfr = *(const short8*)(Wot + n*128 + ks*32 + lgrp*8);
      acc[fc] = mfma16(a, bfr, acc[fc]);
    }
  }
  #pragma unroll
  for(int fc = 0; fc < 8; ++fc){
    int c = fc*16 + lrow;
    float bb = bo[c];
    #pragma unroll
    for(int q = 0; q < 4; ++q){
      int jl = wid*16 + lgrp*4 + q;
      out[((long)i*NN + j0 + jl)*DD + c] = acc[fc][q] + bb;
    }
  }
}

// ---------------------------------------------------------------------------
extern "C" void kernel_launch(void* const* d_in, const int* in_sizes, int n_in,
                              void* d_out, int out_size, void* d_ws, size_t ws_size,
                              hipStream_t stream){
  const float* x   = (const float*)d_in[0];
  const float* na  = (const float*)d_in[1];
  const float* nb  = (const float*)d_in[2];
  const float* Wl  = (const float*)d_in[3];
  const float* bl  = (const float*)d_in[4];
  const float* Wr  = (const float*)d_in[5];
  const float* br  = (const float*)d_in[6];
  const float* Wlg = (const float*)d_in[7];
  const float* blg = (const float*)d_in[8];
  const float* Wrg = (const float*)d_in[9];
  const float* brg = (const float*)d_in[10];
  const float* Wog = (const float*)d_in[11];
  const float* bog = (const float*)d_in[12];
  const float* ona = (const float*)d_in[13];
  const float* onb = (const float*)d_in[14];
  const float* Wo  = (const float*)d_in[15];
  const float* bo  = (const float*)d_in[16];
  float* out = (float*)d_out;

  char* ws = (char*)d_ws;
  const size_t SZ = (size_t)MM*DD*2;                    // 37.75 MB
  unsigned short* xn   = (unsigned short*)(ws);         // region0 (later: mid)
  unsigned short* Lt   = (unsigned short*)(ws + SZ);
  unsigned short* Rt   = (unsigned short*)(ws + 2*SZ);
  unsigned short* gate = (unsigned short*)(ws + 3*SZ);
  unsigned short* Wcat = (unsigned short*)(ws + 4*SZ);
  unsigned short* Wot  = (unsigned short*)(ws + 4*SZ + (size_t)640*128*2);
  unsigned short* mid  = xn;   // xn dead after k_proj; overlay

  k_prep  <<<768, 64, 0, stream>>>(Wl, Wlg, Wr, Wrg, Wog, Wo, Wcat, Wot);
  k_ln_x  <<<MM/4, 256, 0, stream>>>(x, na, nb, xn);
  k_proj  <<<5760, 512, 0, stream>>>(xn, Wcat, bl, blg, br, brg, bog, Lt, Rt, gate);
  k_einsum<<<1152, 256, 0, stream>>>(Rt, Lt, mid);
  k_final <<<dim3(6, 384), 256, 0, stream>>>(mid, gate, ona, onb, Wot, bo, out);
}

// Round 5
// 197.160 us; speedup vs baseline: 1.3411x; 1.0160x over previous
//
#include <hip/hip_runtime.h>
#include <hip/hip_bf16.h>

#define NN 384
#define DD 128
#define MM (NN*NN)   // 147456 rows

typedef __attribute__((ext_vector_type(8))) short short8;
typedef __attribute__((ext_vector_type(4))) float f32x4;

__device__ __forceinline__ unsigned short f2bf(float f){
  unsigned u = __float_as_uint(f);
  u += 0x7fffu + ((u >> 16) & 1u);      // RNE
  return (unsigned short)(u >> 16);
}
__device__ __forceinline__ float bf2f(unsigned short u){
  return __uint_as_float(((unsigned)u) << 16);
}
__device__ __forceinline__ float sigm(float x){
  return 1.0f / (1.0f + __expf(-x));
}
__device__ __forceinline__ unsigned cvtpk(float lo, float hi){
  unsigned r;
  asm("v_cvt_pk_bf16_f32 %0, %1, %2" : "=v"(r) : "v"(lo), "v"(hi));
  return r;
}
__device__ __forceinline__ f32x4 mfma16(short8 a, short8 b, f32x4 c){
  return __builtin_amdgcn_mfma_f32_16x16x32_bf16(a, b, c, 0, 0, 0);
}
// async global->LDS, 16B/lane; LDS base wave-uniform (HW adds lane*16)
__device__ __forceinline__ void gll16(const void* g, void* l){
  __builtin_amdgcn_global_load_lds(
      (const __attribute__((address_space(1))) unsigned int*)g,
      (__attribute__((address_space(3))) unsigned int*)l, 16, 0, 0);
}

// ---------------------------------------------------------------------------
// k_prep: Wcat_t[n][k] bf16 = [Wl|Wlg|Wr|Wrg|Wog]^T (n in [0,640)); Wot = Wo^T.
__global__ void k_prep(const float* __restrict__ Wl, const float* __restrict__ Wlg,
                       const float* __restrict__ Wr, const float* __restrict__ Wrg,
                       const float* __restrict__ Wog, const float* __restrict__ Wo,
                       unsigned short* __restrict__ Wcat, unsigned short* __restrict__ Wot){
  int n = blockIdx.x;           // 0..767
  if(n < 640){
    const float* src; int col;
    if(n < 128){ src = Wl;  col = n; }
    else if(n < 256){ src = Wlg; col = n-128; }
    else if(n < 384){ src = Wr;  col = n-256; }
    else if(n < 512){ src = Wrg; col = n-384; }
    else            { src = Wog; col = n-512; }
    for(int k = threadIdx.x; k < 128; k += 64)
      Wcat[n*128 + k] = f2bf(src[k*128 + col]);
  } else {
    int c = n - 640;
    for(int k = threadIdx.x; k < 128; k += 64)
      Wot[c*128 + k] = f2bf(Wo[k*128 + c]);
  }
}

// ---------------------------------------------------------------------------
// k_ln_x: layernorm rows of x (fp32) -> xn bf16.  One wave per row.
__global__ __launch_bounds__(256) void k_ln_x(const float* __restrict__ x,
    const float* __restrict__ na, const float* __restrict__ nb,
    unsigned short* __restrict__ xn){
  int wid = threadIdx.x >> 6, lane = threadIdx.x & 63;
  long r = (long)blockIdx.x*4 + wid;
  float2 v = *(const float2*)(x + r*DD + lane*2);
  float s  = v.x + v.y;
  float sq = v.x*v.x + v.y*v.y;
  #pragma unroll
  for(int m = 32; m >= 1; m >>= 1){ s += __shfl_xor(s, m); sq += __shfl_xor(sq, m); }
  float mean = s  * (1.0f/128.0f);
  float var  = sq * (1.0f/128.0f) - mean*mean;
  float rstd = rsqrtf(var + 1e-5f);
  float2 a = *(const float2*)(na + lane*2);
  float2 b = *(const float2*)(nb + lane*2);
  unsigned pk = (unsigned)f2bf(a.x*(v.x-mean)*rstd + b.x)
              | ((unsigned)f2bf(a.y*(v.y-mean)*rstd + b.y) << 16);
  *(unsigned*)(xn + r*DD + lane*2) = pk;
}

// ---------------------------------------------------------------------------
// k_proj: persistent L/R projection. 1152 blocks x 256 thr; block b: flavor
//  f = b/288 (d-quarter), unit group w = b%288, units v = w*8+i (v = j*6+kb).
//  Same w across flavors -> same XCD (288 % 8 == 0) -> xn tile L2 reuse.
//  Per wave (ws=L/R side, wd=d-16-half): B frags in REGISTERS loaded once.
//  A tile [64 kk][128 k] double-buffered in LDS via gll16 (pre-swizzled src).
//  Thread's acc q-run = consecutive kk -> packed 8B stores to Lt/Rt[d][j][k].
//  1/384 folded into Lt.  Gate projection moved to k_final.
__global__ __launch_bounds__(256, 4) void k_proj(
    const unsigned short* __restrict__ xn, const unsigned short* __restrict__ Wcat,
    const float* __restrict__ bl, const float* __restrict__ blg,
    const float* __restrict__ br, const float* __restrict__ brg,
    unsigned short* __restrict__ Lt, unsigned short* __restrict__ Rt){
  __shared__ char lds[2][16384];
  const int tid = threadIdx.x;
  const int wid = tid >> 6, lane = tid & 63;
  const int lrow = lane & 15, lgrp = lane >> 4;
  const int b = blockIdx.x;            // 1152 = 4*288
  const int f = b / 288;               // d-quarter
  const int w = b % 288;

  const int ws = wid >> 1;             // 0=L 1=R
  const int wd = wid & 1;              // d-16-half of quarter
  const int d  = f*32 + wd*16 + lrow;

  // B fragments held in registers (L2-resident Wcat), loaded once
  short8 bv[4], bg[4];
  #pragma unroll
  for(int ks = 0; ks < 4; ++ks){
    bv[ks] = *(const short8*)(Wcat + (ws*256 + d)*DD + ks*32 + lgrp*8);
    bg[ks] = *(const short8*)(Wcat + (ws*256 + 128 + d)*DD + ks*32 + lgrp*8);
  }
  const float b0v = (ws ? br  : bl )[d];
  const float b1v = (ws ? brg : blg)[d];
  const float sc  = ws ? 1.0f : (1.0f/384.0f);   // fold einsum 1/n into Lt
  unsigned short* const base = (ws ? Rt : Lt) + (long)d*MM;

  auto stage = [&](int buf, int v){
    int j = v/6, kb = v%6;
    int rsub = lane >> 4, c = lane & 15;
    #pragma unroll
    for(int p = 0; p < 4; ++p){
      int r0 = p*16 + wid*4;
      int r = r0 + rsub;
      gll16(xn + ((long)(kb*64 + r)*NN + j)*DD + (c ^ (r & 7))*8, &lds[buf][r0*256]);
    }
  };

  stage(0, w*8);
  __syncthreads();
  int cur = 0;
  for(int i = 0; i < 8; ++i){
    int v = w*8 + i;
    if(i < 7) stage(cur^1, v+1);       // prefetch flies over compute+epilogue

    f32x4 zero = {0.f,0.f,0.f,0.f};
    f32x4 acc[4][2];
    #pragma unroll
    for(int a1=0;a1<4;++a1){ acc[a1][0] = zero; acc[a1][1] = zero; }

    #pragma unroll
    for(int ks = 0; ks < 4; ++ks){
      #pragma unroll
      for(int fr = 0; fr < 4; ++fr){
        int r = fr*16 + lrow;
        short8 af = *(const short8*)(&lds[cur][r*256 + (((ks*4+lgrp)*16) ^ ((r&7)<<4))]);
        acc[fr][0] = mfma16(af, bv[ks], acc[fr][0]);
        acc[fr][1] = mfma16(af, bg[ks], acc[fr][1]);
      }
    }

    int j = v/6, kb = v%6;
    unsigned short* dst = base + (long)j*NN + kb*64;
    #pragma unroll
    for(int fr = 0; fr < 4; ++fr){
      float v0 = (acc[fr][0][0] + b0v)*sigm(acc[fr][1][0] + b1v)*sc;
      float v1 = (acc[fr][0][1] + b0v)*sigm(acc[fr][1][1] + b1v)*sc;
      float v2 = (acc[fr][0][2] + b0v)*sigm(acc[fr][1][2] + b1v)*sc;
      float v3 = (acc[fr][0][3] + b0v)*sigm(acc[fr][1][3] + b1v)*sc;
      uint2 pk; pk.x = cvtpk(v0, v1); pk.y = cvtpk(v2, v3);
      *(uint2*)(dst + fr*16 + lgrp*4) = pk;
    }
    __syncthreads();                   // prefetch landed; buffers swap
    cur ^= 1;
  }
}

// ---------------------------------------------------------------------------
// k_einsum: per d: mid[d][i][j] = sum_k Rt[d][i][k]*Lt[d][j][k]  (1/384 folded
// into Lt).  A=Lt j-rows, B=Rt i-rows -> acc q-run = consecutive j -> packed
// 8B direct stores.  Double-buffered gll16; same-d blocks XCD-grouped.
__global__ __launch_bounds__(256) void k_einsum(
    const unsigned short* __restrict__ Rt, const unsigned short* __restrict__ Lt,
    unsigned short* __restrict__ mid){
  __shared__ char lds[65536];
  const int b = blockIdx.x;              // 1152 = 8 * 144
  const int xcd = b & 7, slot = b >> 3;
  const int d = (slot/9)*8 + xcd;
  const int t = slot % 9;
  const int it = t/3, jt = t%3;
  const int i0 = it*128, j0 = jt*128;
  const unsigned short* Abase = Lt + (long)d*MM;   // j-rows
  const unsigned short* Bbase = Rt + (long)d*MM;   // i-rows
  const int wid = threadIdx.x >> 6, lane = threadIdx.x & 63;
  const int wr = wid >> 1, wc = wid & 1;
  const int lrow = lane & 15, lgrp = lane >> 4;

  auto stage = [&](int buf, int kt){
    int k = kt*64;
    int c = lane & 7;
    #pragma unroll
    for(int t8 = 0; t8 < 8; ++t8){
      int rr = wid*64 + t8*8 + (lane >> 3);   // 0..255 (first 128 = A rows)
      int r = rr & 127;
      const unsigned short* src = (rr < 128) ? (Abase + (long)(j0+r)*NN + k)
                                             : (Bbase + (long)(i0+r)*NN + k);
      gll16(src + (c ^ (r & 7))*8, &lds[buf*32768 + (wid*64 + t8*8)*128]);
    }
  };

  f32x4 zero = {0.f,0.f,0.f,0.f};
  f32x4 acc[4][4];                       // [fj][fi]
  #pragma unroll
  for(int a1 = 0; a1 < 4; ++a1)
    #pragma unroll
    for(int a2 = 0; a2 < 4; ++a2) acc[a1][a2] = zero;

  stage(0, 0);
  __syncthreads();
  for(int kt = 0; kt < 6; ++kt){
    int cur = kt & 1;
    if(kt < 5) stage(cur ^ 1, kt + 1);
    const int base = cur*32768;
    #pragma unroll
    for(int ks = 0; ks < 2; ++ks){
      short8 af[4], bf[4];
      #pragma unroll
      for(int f = 0; f < 4; ++f){
        int rj = wr*64 + f*16 + lrow;
        af[f] = *(const short8*)(&lds[base + rj*128 + (((ks*4+lgrp)*16) ^ ((rj & 7) << 4))]);
        int ri = wc*64 + f*16 + lrow;
        bf[f] = *(const short8*)(&lds[base + 16384 + ri*128 + (((ks*4+lgrp)*16) ^ ((ri & 7) << 4))]);
      }
      #pragma unroll
      for(int fj = 0; fj < 4; ++fj)
        #pragma unroll
        for(int fi = 0; fi < 4; ++fi)
          acc[fj][fi] = mfma16(af[fj], bf[fi], acc[fj][fi]);
    }
    __syncthreads();
  }

  #pragma unroll
  for(int fj = 0; fj < 4; ++fj){
    int j = j0 + wr*64 + fj*16 + lgrp*4;
    #pragma unroll
    for(int fi = 0; fi < 4; ++fi){
      int i = i0 + wc*64 + fi*16 + lrow;
      uint2 pk;
      pk.x = cvtpk(acc[fj][fi][0], acc[fj][fi][1]);
      pk.y = cvtpk(acc[fj][fi][2], acc[fj][fi][3]);
      *(uint2*)(mid + (long)d*MM + (long)i*NN + j) = pk;
    }
  }
}

// ---------------------------------------------------------------------------
// k_final: per (i, 64-wide j strip):
//   gather mid[d][i][j] -> midt; stage xn strip; gate = sigm(xn@Wog+bog) via
//   MFMA -> glds; LN(midt)*gate -> vlds(=slds); MFMA vs Wo^T; +bo; fp32 out.
__global__ __launch_bounds__(256) void k_final(
    const unsigned short* __restrict__ mid, const unsigned short* __restrict__ xn,
    const unsigned short* __restrict__ Wcat,
    const float* __restrict__ bog,
    const float* __restrict__ ona, const float* __restrict__ onb,
    const unsigned short* __restrict__ Wot, const float* __restrict__ bo,
    float* __restrict__ out){
  __shared__ unsigned short midt[64][144];   // bf16, 288B rows (16B aligned)
  __shared__ char slds[16384];               // xn strip; later vlds
  __shared__ char glds[16384];               // gate tile [64 m][128 c] bf16 swz
  const int tid = threadIdx.x;
  const int wid = tid >> 6, lane = tid & 63;
  const int lrow = lane & 15, lgrp = lane >> 4;
  const int i = blockIdx.y;
  const int j0 = blockIdx.x*64;

  { // async stage xn strip: rows m = i*NN + j0 + r, r<64 (contiguous)
    int rsub = lane >> 4, c = lane & 15;
    #pragma unroll
    for(int p = 0; p < 4; ++p){
      int r0 = p*16 + wid*4;
      int r = r0 + rsub;
      gll16(xn + ((long)i*NN + j0 + r)*DD + (c ^ (r & 7))*8, &slds[r0*256]);
    }
  }
  // Wog fragments (L2)
  const int wc = wid;
  short8 ag[2][4];
  #pragma unroll
  for(int cf = 0; cf < 2; ++cf)
    #pragma unroll
    for(int ks = 0; ks < 4; ++ks)
      ag[cf][ks] = *(const short8*)(Wcat + (512 + wc*32 + cf*16 + lrow)*DD + ks*32 + lgrp*8);

  { // gather mid (bf16 straight into LDS)
    int jp = tid & 15, dr = tid >> 4;
    #pragma unroll
    for(int pass = 0; pass < 8; ++pass){
      int dd = pass*16 + dr;
      uint2 v = *(const uint2*)(mid + (long)dd*MM + (long)i*NN + j0 + jp*4);
      midt[jp*4+0][dd] = (unsigned short)(v.x & 0xffffu);
      midt[jp*4+1][dd] = (unsigned short)(v.x >> 16);
      midt[jp*4+2][dd] = (unsigned short)(v.y & 0xffffu);
      midt[jp*4+3][dd] = (unsigned short)(v.y >> 16);
    }
  }
  __syncthreads();                           // slds + midt ready

  { // gate MFMA: A=Wog^T cols, B=xn rows -> acc c-run
    f32x4 zero = {0.f,0.f,0.f,0.f};
    f32x4 accg[2][4];
    #pragma unroll
    for(int a1=0;a1<2;++a1)
      #pragma unroll
      for(int a2=0;a2<4;++a2) accg[a1][a2] = zero;
    #pragma unroll
    for(int ks = 0; ks < 4; ++ks){
      short8 bx[4];
      #pragma unroll
      for(int mf = 0; mf < 4; ++mf){
        int r = mf*16 + lrow;
        bx[mf] = *(const short8*)(&slds[r*256 + (((ks*4+lgrp)*16) ^ ((r&7)<<4))]);
      }
      #pragma unroll
      for(int cf = 0; cf < 2; ++cf)
        #pragma unroll
        for(int mf = 0; mf < 4; ++mf)
          accg[cf][mf] = mfma16(ag[cf][ks], bx[mf], accg[cf][mf]);
    }
    #pragma unroll
    for(int cf = 0; cf < 2; ++cf){
      int c0 = wc*32 + cf*16 + lgrp*4;
      float4 b4 = *(const float4*)(bog + c0);
      #pragma unroll
      for(int mf = 0; mf < 4; ++mf){
        int rr = mf*16 + lrow;
        uint2 pk;
        pk.x = cvtpk(sigm(accg[cf][mf][0] + b4.x), sigm(accg[cf][mf][1] + b4.y));
        pk.y = cvtpk(sigm(accg[cf][mf][2] + b4.z), sigm(accg[cf][mf][3] + b4.w));
        *(uint2*)(&glds[rr*256 + ((c0*2) ^ ((rr&7)<<4))]) = pk;
      }
    }
  }
  __syncthreads();                           // glds ready; slds now free

  { // LN + gate, 4 threads per j-row (32 d each) -> vlds(=slds)
    int j = tid >> 2, s = tid & 3;
    float vals[32];
    float sum = 0.f, sq = 0.f;
    #pragma unroll
    for(int o8 = 0; o8 < 4; ++o8){
      short8 h = *(const short8*)(&midt[j][s*32 + o8*8]);
      #pragma unroll
      for(int q = 0; q < 8; ++q){
        float vq = bf2f((unsigned short)h[q]);
        vals[o8*8+q] = vq; sum += vq; sq += vq*vq;
      }
    }
    #pragma unroll
    for(int m = 1; m < 4; m <<= 1){ sum += __shfl_xor(sum, m); sq += __shfl_xor(sq, m); }
    float mean = sum*(1.f/128.f);
    float var  = sq *(1.f/128.f) - mean*mean;
    float rstd = rsqrtf(var + 1e-5f);
    #pragma unroll
    for(int o = 0; o < 32; o += 4){
      int dd = s*32 + o;
      uint2 gv = *(const uint2*)(&glds[j*256 + ((dd*2) ^ ((j&7)<<4))]);
      float g0 = bf2f((unsigned short)(gv.x & 0xffffu));
      float g1 = bf2f((unsigned short)(gv.x >> 16));
      float g2 = bf2f((unsigned short)(gv.y & 0xffffu));
      float g3 = bf2f((unsigned short)(gv.y >> 16));
      float4 a4 = *(const float4*)(ona + dd);
      float4 b4 = *(const float4*)(onb + dd);
      float v0 = (a4.x*(vals[o]  -mean)*rstd + b4.x)*g0;
      float v1 = (a4.y*(vals[o+1]-mean)*rstd + b4.y)*g1;
      float v2 = (a4.z*(vals[o+2]-mean)*rstd + b4.z)*g2;
      float v3 = (a4.w*(vals[o+3]-mean)*rstd + b4.w)*g3;
      uint2 pk; pk.x = cvtpk(v0, v1); pk.y = cvtpk(v2, v3);
      *(uint2*)(&slds[j*256 + ((dd*2) ^ ((j&7)<<4))]) = pk;
    }
  }
  __syncthreads();

  { // out MFMA: each wave = 16 j-rows x all 128 c
    f32x4 zero = {0.f,0.f,0.f,0.f};
    f32x4 acc[8];
    #pragma unroll
    for(int fc = 0; fc < 8; ++fc) acc[fc] = zero;
    #pragma unroll 1
    for(int ks = 0; ks < 4; ++ks){
      int row = wid*16 + lrow;
      short8 a = *(const short8*)(&slds[row*256 + (((ks*4+lgrp)*16) ^ ((row & 7) << 4))]);
      #pragma unroll
      for(int fc = 0; fc < 8; ++fc){
        int n = fc*16 + lrow;
        short8 bfr = *(const short8*)(Wot + n*DD + ks*32 + lgrp*8);
        acc[fc] = mfma16(a, bfr, acc[fc]);
      }
    }
    #pragma unroll
    for(int fc = 0; fc < 8; ++fc){
      int c = fc*16 + lrow;
      float bb = bo[c];
      #pragma unroll
      for(int q = 0; q < 4; ++q){
        int jl = wid*16 + lgrp*4 + q;
        out[((long)i*NN + j0 + jl)*DD + c] = acc[fc][q] + bb;
      }
    }
  }
}

// ---------------------------------------------------------------------------
extern "C" void kernel_launch(void* const* d_in, const int* in_sizes, int n_in,
                              void* d_out, int out_size, void* d_ws, size_t ws_size,
                              hipStream_t stream){
  const float* x   = (const float*)d_in[0];
  const float* na  = (const float*)d_in[1];
  const float* nb  = (const float*)d_in[2];
  const float* Wl  = (const float*)d_in[3];
  const float* bl  = (const float*)d_in[4];
  const float* Wr  = (const float*)d_in[5];
  const float* br  = (const float*)d_in[6];
  const float* Wlg = (const float*)d_in[7];
  const float* blg = (const float*)d_in[8];
  const float* Wrg = (const float*)d_in[9];
  const float* brg = (const float*)d_in[10];
  const float* Wog = (const float*)d_in[11];
  const float* bog = (const float*)d_in[12];
  const float* ona = (const float*)d_in[13];
  const float* onb = (const float*)d_in[14];
  const float* Wo  = (const float*)d_in[15];
  const float* bo  = (const float*)d_in[16];
  float* out = (float*)d_out;

  char* ws = (char*)d_ws;
  const size_t SZ = (size_t)MM*DD*2;                    // 37.75 MB
  unsigned short* xn   = (unsigned short*)(ws);         // LIVE until k_final
  unsigned short* Lt   = (unsigned short*)(ws + SZ);
  unsigned short* Rt   = (unsigned short*)(ws + 2*SZ);
  unsigned short* mid  = (unsigned short*)(ws + 3*SZ);  // old gate slot
  unsigned short* Wcat = (unsigned short*)(ws + 4*SZ);
  unsigned short* Wot  = (unsigned short*)(ws + 4*SZ + (size_t)640*128*2);

  k_prep  <<<768, 64, 0, stream>>>(Wl, Wlg, Wr, Wrg, Wog, Wo, Wcat, Wot);
  k_ln_x  <<<MM/4, 256, 0, stream>>>(x, na, nb, xn);
  k_proj  <<<1152, 256, 0, stream>>>(xn, Wcat, bl, blg, br, brg, Lt, Rt);
  k_einsum<<<1152, 256, 0, stream>>>(Rt, Lt, mid);
  k_final <<<dim3(6, 384), 256, 0, stream>>>(mid, xn, Wcat, bog, ona, onb, Wot, bo, out);
}

// Round 6
// 180.146 us; speedup vs baseline: 1.4677x; 1.0944x over previous
//
#include <hip/hip_runtime.h>
#include <hip/hip_bf16.h>

#define NN 384
#define DD 128
#define MM (NN*NN)   // 147456 rows

typedef __attribute__((ext_vector_type(8))) short short8;
typedef __attribute__((ext_vector_type(4))) float f32x4;

__device__ __forceinline__ unsigned short f2bf(float f){
  unsigned u = __float_as_uint(f);
  u += 0x7fffu + ((u >> 16) & 1u);      // RNE
  return (unsigned short)(u >> 16);
}
__device__ __forceinline__ float bf2f(unsigned short u){
  return __uint_as_float(((unsigned)u) << 16);
}
__device__ __forceinline__ float sigm(float x){
  return 1.0f / (1.0f + __expf(-x));
}
__device__ __forceinline__ unsigned cvtpk(float lo, float hi){
  unsigned r;
  asm("v_cvt_pk_bf16_f32 %0, %1, %2" : "=v"(r) : "v"(lo), "v"(hi));
  return r;
}
__device__ __forceinline__ f32x4 mfma16(short8 a, short8 b, f32x4 c){
  return __builtin_amdgcn_mfma_f32_16x16x32_bf16(a, b, c, 0, 0, 0);
}
// async global->LDS, 16B/lane; LDS base wave-uniform (HW adds lane*16)
__device__ __forceinline__ void gll16(const void* g, void* l){
  __builtin_amdgcn_global_load_lds(
      (const __attribute__((address_space(1))) unsigned int*)g,
      (__attribute__((address_space(3))) unsigned int*)l, 16, 0, 0);
}

// ---------------------------------------------------------------------------
// k_prep: Wcat_t[n][k] bf16 = [Wl|Wlg|Wr|Wrg|Wog]^T (n in [0,640)); Wot = Wo^T.
__global__ void k_prep(const float* __restrict__ Wl, const float* __restrict__ Wlg,
                       const float* __restrict__ Wr, const float* __restrict__ Wrg,
                       const float* __restrict__ Wog, const float* __restrict__ Wo,
                       unsigned short* __restrict__ Wcat, unsigned short* __restrict__ Wot){
  int n = blockIdx.x;           // 0..767
  if(n < 640){
    const float* src; int col;
    if(n < 128){ src = Wl;  col = n; }
    else if(n < 256){ src = Wlg; col = n-128; }
    else if(n < 384){ src = Wr;  col = n-256; }
    else if(n < 512){ src = Wrg; col = n-384; }
    else            { src = Wog; col = n-512; }
    for(int k = threadIdx.x; k < 128; k += 64)
      Wcat[n*128 + k] = f2bf(src[k*128 + col]);
  } else {
    int c = n - 640;
    for(int k = threadIdx.x; k < 128; k += 64)
      Wot[c*128 + k] = f2bf(Wo[k*128 + c]);
  }
}

// ---------------------------------------------------------------------------
// k_ln_x: layernorm rows of x (fp32) -> xn bf16.  One wave per row.
__global__ __launch_bounds__(256) void k_ln_x(const float* __restrict__ x,
    const float* __restrict__ na, const float* __restrict__ nb,
    unsigned short* __restrict__ xn){
  int wid = threadIdx.x >> 6, lane = threadIdx.x & 63;
  long r = (long)blockIdx.x*4 + wid;
  float2 v = *(const float2*)(x + r*DD + lane*2);
  float s  = v.x + v.y;
  float sq = v.x*v.x + v.y*v.y;
  #pragma unroll
  for(int m = 32; m >= 1; m >>= 1){ s += __shfl_xor(s, m); sq += __shfl_xor(sq, m); }
  float mean = s  * (1.0f/128.0f);
  float var  = sq * (1.0f/128.0f) - mean*mean;
  float rstd = rsqrtf(var + 1e-5f);
  float2 a = *(const float2*)(na + lane*2);
  float2 b = *(const float2*)(nb + lane*2);
  unsigned pk = (unsigned)f2bf(a.x*(v.x-mean)*rstd + b.x)
              | ((unsigned)f2bf(a.y*(v.y-mean)*rstd + b.y) << 16);
  *(unsigned*)(xn + r*DD + lane*2) = pk;
}

// ---------------------------------------------------------------------------
// k_proj: persistent L/R projection. 1152 blocks x 256 thr; block b: flavor
//  f = b/288 (d-quarter), unit group w = b%288, units v = w*8+i (v = j*6+kb).
//  B frags in registers loaded once; A tile double-buffered via gll16.
//  Thread's acc q-run = consecutive kk -> packed 8B stores to Lt/Rt[d][j][k].
//  1/384 folded into Lt.
__global__ __launch_bounds__(256, 4) void k_proj(
    const unsigned short* __restrict__ xn, const unsigned short* __restrict__ Wcat,
    const float* __restrict__ bl, const float* __restrict__ blg,
    const float* __restrict__ br, const float* __restrict__ brg,
    unsigned short* __restrict__ Lt, unsigned short* __restrict__ Rt){
  __shared__ char lds[2][16384];
  const int tid = threadIdx.x;
  const int wid = tid >> 6, lane = tid & 63;
  const int lrow = lane & 15, lgrp = lane >> 4;
  const int b = blockIdx.x;            // 1152 = 4*288
  const int f = b / 288;               // d-quarter
  const int w = b % 288;

  const int ws = wid >> 1;             // 0=L 1=R
  const int wd = wid & 1;              // d-16-half of quarter
  const int d  = f*32 + wd*16 + lrow;

  short8 bv[4], bg[4];
  #pragma unroll
  for(int ks = 0; ks < 4; ++ks){
    bv[ks] = *(const short8*)(Wcat + (ws*256 + d)*DD + ks*32 + lgrp*8);
    bg[ks] = *(const short8*)(Wcat + (ws*256 + 128 + d)*DD + ks*32 + lgrp*8);
  }
  const float b0v = (ws ? br  : bl )[d];
  const float b1v = (ws ? brg : blg)[d];
  const float sc  = ws ? 1.0f : (1.0f/384.0f);   // fold einsum 1/n into Lt
  unsigned short* const base = (ws ? Rt : Lt) + (long)d*MM;

  auto stage = [&](int buf, int v){
    int j = v/6, kb = v%6;
    int rsub = lane >> 4, c = lane & 15;
    #pragma unroll
    for(int p = 0; p < 4; ++p){
      int r0 = p*16 + wid*4;
      int r = r0 + rsub;
      gll16(xn + ((long)(kb*64 + r)*NN + j)*DD + (c ^ (r & 7))*8, &lds[buf][r0*256]);
    }
  };

  stage(0, w*8);
  __syncthreads();
  int cur = 0;
  for(int i = 0; i < 8; ++i){
    int v = w*8 + i;
    if(i < 7) stage(cur^1, v+1);       // prefetch flies over compute+epilogue

    f32x4 zero = {0.f,0.f,0.f,0.f};
    f32x4 acc[4][2];
    #pragma unroll
    for(int a1=0;a1<4;++a1){ acc[a1][0] = zero; acc[a1][1] = zero; }

    #pragma unroll
    for(int ks = 0; ks < 4; ++ks){
      #pragma unroll
      for(int fr = 0; fr < 4; ++fr){
        int r = fr*16 + lrow;
        short8 af = *(const short8*)(&lds[cur][r*256 + (((ks*4+lgrp)*16) ^ ((r&7)<<4))]);
        acc[fr][0] = mfma16(af, bv[ks], acc[fr][0]);
        acc[fr][1] = mfma16(af, bg[ks], acc[fr][1]);
      }
    }

    int j = v/6, kb = v%6;
    unsigned short* dst = base + (long)j*NN + kb*64;
    #pragma unroll
    for(int fr = 0; fr < 4; ++fr){
      float v0 = (acc[fr][0][0] + b0v)*sigm(acc[fr][1][0] + b1v)*sc;
      float v1 = (acc[fr][0][1] + b0v)*sigm(acc[fr][1][1] + b1v)*sc;
      float v2 = (acc[fr][0][2] + b0v)*sigm(acc[fr][1][2] + b1v)*sc;
      float v3 = (acc[fr][0][3] + b0v)*sigm(acc[fr][1][3] + b1v)*sc;
      uint2 pk; pk.x = cvtpk(v0, v1); pk.y = cvtpk(v2, v3);
      *(uint2*)(dst + fr*16 + lgrp*4) = pk;
    }
    __syncthreads();                   // prefetch landed; buffers swap
    cur ^= 1;
  }
}

// ---------------------------------------------------------------------------
// k_einsum: per d: mid[d][i][j] = sum_k Rt[d][i][k]*Lt[d][j][k]  (1/384 folded
// into Lt).  A=Lt j-rows, B=Rt i-rows -> acc q-run = consecutive j -> packed
// 8B direct stores.  Double-buffered gll16; same-d blocks XCD-grouped.
__global__ __launch_bounds__(256) void k_einsum(
    const unsigned short* __restrict__ Rt, const unsigned short* __restrict__ Lt,
    unsigned short* __restrict__ mid){
  __shared__ char lds[65536];
  const int b = blockIdx.x;              // 1152 = 8 * 144
  const int xcd = b & 7, slot = b >> 3;
  const int d = (slot/9)*8 + xcd;
  const int t = slot % 9;
  const int it = t/3, jt = t%3;
  const int i0 = it*128, j0 = jt*128;
  const unsigned short* Abase = Lt + (long)d*MM;   // j-rows
  const unsigned short* Bbase = Rt + (long)d*MM;   // i-rows
  const int wid = threadIdx.x >> 6, lane = threadIdx.x & 63;
  const int wr = wid >> 1, wc = wid & 1;
  const int lrow = lane & 15, lgrp = lane >> 4;

  auto stage = [&](int buf, int kt){
    int k = kt*64;
    int c = lane & 7;
    #pragma unroll
    for(int t8 = 0; t8 < 8; ++t8){
      int rr = wid*64 + t8*8 + (lane >> 3);   // 0..255 (first 128 = A rows)
      int r = rr & 127;
      const unsigned short* src = (rr < 128) ? (Abase + (long)(j0+r)*NN + k)
                                             : (Bbase + (long)(i0+r)*NN + k);
      gll16(src + (c ^ (r & 7))*8, &lds[buf*32768 + (wid*64 + t8*8)*128]);
    }
  };

  f32x4 zero = {0.f,0.f,0.f,0.f};
  f32x4 acc[4][4];                       // [fj][fi]
  #pragma unroll
  for(int a1 = 0; a1 < 4; ++a1)
    #pragma unroll
    for(int a2 = 0; a2 < 4; ++a2) acc[a1][a2] = zero;

  stage(0, 0);
  __syncthreads();
  for(int kt = 0; kt < 6; ++kt){
    int cur = kt & 1;
    if(kt < 5) stage(cur ^ 1, kt + 1);
    const int base = cur*32768;
    #pragma unroll
    for(int ks = 0; ks < 2; ++ks){
      short8 af[4], bf[4];
      #pragma unroll
      for(int f = 0; f < 4; ++f){
        int rj = wr*64 + f*16 + lrow;
        af[f] = *(const short8*)(&lds[base + rj*128 + (((ks*4+lgrp)*16) ^ ((rj & 7) << 4))]);
        int ri = wc*64 + f*16 + lrow;
        bf[f] = *(const short8*)(&lds[base + 16384 + ri*128 + (((ks*4+lgrp)*16) ^ ((ri & 7) << 4))]);
      }
      #pragma unroll
      for(int fj = 0; fj < 4; ++fj)
        #pragma unroll
        for(int fi = 0; fi < 4; ++fi)
          acc[fj][fi] = mfma16(af[fj], bf[fi], acc[fj][fi]);
    }
    __syncthreads();
  }

  #pragma unroll
  for(int fj = 0; fj < 4; ++fj){
    int j = j0 + wr*64 + fj*16 + lgrp*4;
    #pragma unroll
    for(int fi = 0; fi < 4; ++fi){
      int i = i0 + wc*64 + fi*16 + lrow;
      uint2 pk;
      pk.x = cvtpk(acc[fj][fi][0], acc[fj][fi][1]);
      pk.y = cvtpk(acc[fj][fi][2], acc[fj][fi][3]);
      *(uint2*)(mid + (long)d*MM + (long)i*NN + j) = pk;
    }
  }
}

// ---------------------------------------------------------------------------
// k_final: per (i, 64-wide j strip). One LDS buffer (slds) serves three lives:
//   xn strip -> gate tile -> val tile (in-place LN rewrite). midt holds the
//   gathered mid strip. Out-projection uses operand-role swap (A=Wot rows=c)
//   so each thread stores float4 (64B-coalesced segments).
__global__ __launch_bounds__(256) void k_final(
    const unsigned short* __restrict__ mid, const unsigned short* __restrict__ xn,
    const unsigned short* __restrict__ Wcat,
    const float* __restrict__ bog,
    const float* __restrict__ ona, const float* __restrict__ onb,
    const unsigned short* __restrict__ Wot, const float* __restrict__ bo,
    float* __restrict__ out){
  __shared__ unsigned short midt[64][136];   // 17.4KB, 272B rows
  __shared__ char slds[16384];               // xn -> gate -> val
  const int tid = threadIdx.x;
  const int wid = tid >> 6, lane = tid & 63;
  const int lrow = lane & 15, lgrp = lane >> 4;
  const int i = blockIdx.y;
  const int j0 = blockIdx.x*64;
  const int wc = wid;

  { // async stage xn strip: rows m = i*NN + j0 + r, r<64 (contiguous)
    int rsub = lane >> 4, c = lane & 15;
    #pragma unroll
    for(int p = 0; p < 4; ++p){
      int r0 = p*16 + wid*4;
      int r = r0 + rsub;
      gll16(xn + ((long)i*NN + j0 + r)*DD + (c ^ (r & 7))*8, &slds[r0*256]);
    }
  }
  // Wog fragments (L2)
  short8 ag[2][4];
  #pragma unroll
  for(int cf = 0; cf < 2; ++cf)
    #pragma unroll
    for(int ks = 0; ks < 4; ++ks)
      ag[cf][ks] = *(const short8*)(Wcat + (512 + wc*32 + cf*16 + lrow)*DD + ks*32 + lgrp*8);

  { // gather mid (bf16 straight into LDS)
    int jp = tid & 15, dr = tid >> 4;
    #pragma unroll
    for(int pass = 0; pass < 8; ++pass){
      int dd = pass*16 + dr;
      uint2 v = *(const uint2*)(mid + (long)dd*MM + (long)i*NN + j0 + jp*4);
      midt[jp*4+0][dd] = (unsigned short)(v.x & 0xffffu);
      midt[jp*4+1][dd] = (unsigned short)(v.x >> 16);
      midt[jp*4+2][dd] = (unsigned short)(v.y & 0xffffu);
      midt[jp*4+3][dd] = (unsigned short)(v.y >> 16);
    }
  }
  __syncthreads();                           // #1: slds(xn) + midt ready

  // gate MFMA: A=Wog^T cols (c), B=xn rows (m) -> thread q-run = consecutive c
  f32x4 zero = {0.f,0.f,0.f,0.f};
  f32x4 accg[2][4];
  #pragma unroll
  for(int a1=0;a1<2;++a1)
    #pragma unroll
    for(int a2=0;a2<4;++a2) accg[a1][a2] = zero;
  #pragma unroll
  for(int ks = 0; ks < 4; ++ks){
    short8 bx[4];
    #pragma unroll
    for(int mf = 0; mf < 4; ++mf){
      int r = mf*16 + lrow;
      bx[mf] = *(const short8*)(&slds[r*256 + (((ks*4+lgrp)*16) ^ ((r&7)<<4))]);
    }
    #pragma unroll
    for(int cf = 0; cf < 2; ++cf)
      #pragma unroll
      for(int mf = 0; mf < 4; ++mf)
        accg[cf][mf] = mfma16(ag[cf][ks], bx[mf], accg[cf][mf]);
  }

  // Wot fragments (L2) — issued here so latency hides under gate-write + LN
  short8 aw[2][4];
  #pragma unroll
  for(int cf = 0; cf < 2; ++cf)
    #pragma unroll
    for(int ks = 0; ks < 4; ++ks)
      aw[cf][ks] = *(const short8*)(Wot + (wc*32 + cf*16 + lrow)*DD + ks*32 + lgrp*8);

  __syncthreads();                           // #2: all xn reads done

  { // write gate into slds (reuse)
    #pragma unroll
    for(int cf = 0; cf < 2; ++cf){
      int c0 = wc*32 + cf*16 + lgrp*4;
      float4 b4 = *(const float4*)(bog + c0);
      #pragma unroll
      for(int mf = 0; mf < 4; ++mf){
        int rr = mf*16 + lrow;
        uint2 pk;
        pk.x = cvtpk(sigm(accg[cf][mf][0] + b4.x), sigm(accg[cf][mf][1] + b4.y));
        pk.y = cvtpk(sigm(accg[cf][mf][2] + b4.z), sigm(accg[cf][mf][3] + b4.w));
        *(uint2*)(&slds[rr*256 + ((c0*2) ^ ((rr&7)<<4))]) = pk;
      }
    }
  }
  __syncthreads();                           // #3: gate ready

  { // LN + gate, 4 threads per j-row (32 d each); val overwrites gate in-place
    int j = tid >> 2, s = tid & 3;
    float vals[32];
    float sum = 0.f, sq = 0.f;
    #pragma unroll
    for(int o8 = 0; o8 < 4; ++o8){
      short8 h = *(const short8*)(&midt[j][s*32 + o8*8]);
      #pragma unroll
      for(int q = 0; q < 8; ++q){
        float vq = bf2f((unsigned short)h[q]);
        vals[o8*8+q] = vq; sum += vq; sq += vq*vq;
      }
    }
    #pragma unroll
    for(int m = 1; m < 4; m <<= 1){ sum += __shfl_xor(sum, m); sq += __shfl_xor(sq, m); }
    float mean = sum*(1.f/128.f);
    float var  = sq *(1.f/128.f) - mean*mean;
    float rstd = rsqrtf(var + 1e-5f);
    #pragma unroll
    for(int o = 0; o < 32; o += 4){
      int dd = s*32 + o;
      char* gp = &slds[j*256 + ((dd*2) ^ ((j&7)<<4))];
      uint2 gv = *(uint2*)gp;
      float g0 = bf2f((unsigned short)(gv.x & 0xffffu));
      float g1 = bf2f((unsigned short)(gv.x >> 16));
      float g2 = bf2f((unsigned short)(gv.y & 0xffffu));
      float g3 = bf2f((unsigned short)(gv.y >> 16));
      float4 a4 = *(const float4*)(ona + dd);
      float4 b4 = *(const float4*)(onb + dd);
      float v0 = (a4.x*(vals[o]  -mean)*rstd + b4.x)*g0;
      float v1 = (a4.y*(vals[o+1]-mean)*rstd + b4.y)*g1;
      float v2 = (a4.z*(vals[o+2]-mean)*rstd + b4.z)*g2;
      float v3 = (a4.w*(vals[o+3]-mean)*rstd + b4.w)*g3;
      uint2 pk; pk.x = cvtpk(v0, v1); pk.y = cvtpk(v2, v3);
      *(uint2*)gp = pk;                      // same thread RW: no extra barrier
    }
  }
  __syncthreads();                           // #4: val ready

  { // out MFMA: A=Wot rows (c), B=val rows (j) -> q-run = consecutive c
    f32x4 acco[2][4];
    #pragma unroll
    for(int a1=0;a1<2;++a1)
      #pragma unroll
      for(int a2=0;a2<4;++a2) acco[a1][a2] = zero;
    #pragma unroll
    for(int ks = 0; ks < 4; ++ks){
      short8 bx[4];
      #pragma unroll
      for(int mf = 0; mf < 4; ++mf){
        int r = mf*16 + lrow;
        bx[mf] = *(const short8*)(&slds[r*256 + (((ks*4+lgrp)*16) ^ ((r&7)<<4))]);
      }
      #pragma unroll
      for(int cf = 0; cf < 2; ++cf)
        #pragma unroll
        for(int mf = 0; mf < 4; ++mf)
          acco[cf][mf] = mfma16(aw[cf][ks], bx[mf], acco[cf][mf]);
    }
    #pragma unroll
    for(int cf = 0; cf < 2; ++cf){
      int c0 = wc*32 + cf*16 + lgrp*4;
      float4 b4 = *(const float4*)(bo + c0);
      #pragma unroll
      for(int mf = 0; mf < 4; ++mf){
        int jl = mf*16 + lrow;
        float4 v;
        v.x = acco[cf][mf][0] + b4.x;
        v.y = acco[cf][mf][1] + b4.y;
        v.z = acco[cf][mf][2] + b4.z;
        v.w = acco[cf][mf][3] + b4.w;
        *(float4*)(out + ((long)i*NN + j0 + jl)*DD + c0) = v;
      }
    }
  }
}

// ---------------------------------------------------------------------------
extern "C" void kernel_launch(void* const* d_in, const int* in_sizes, int n_in,
                              void* d_out, int out_size, void* d_ws, size_t ws_size,
                              hipStream_t stream){
  const float* x   = (const float*)d_in[0];
  const float* na  = (const float*)d_in[1];
  const float* nb  = (const float*)d_in[2];
  const float* Wl  = (const float*)d_in[3];
  const float* bl  = (const float*)d_in[4];
  const float* Wr  = (const float*)d_in[5];
  const float* br  = (const float*)d_in[6];
  const float* Wlg = (const float*)d_in[7];
  const float* blg = (const float*)d_in[8];
  const float* Wrg = (const float*)d_in[9];
  const float* brg = (const float*)d_in[10];
  const float* Wog = (const float*)d_in[11];
  const float* bog = (const float*)d_in[12];
  const float* ona = (const float*)d_in[13];
  const float* onb = (const float*)d_in[14];
  const float* Wo  = (const float*)d_in[15];
  const float* bo  = (const float*)d_in[16];
  float* out = (float*)d_out;

  char* ws = (char*)d_ws;
  const size_t SZ = (size_t)MM*DD*2;                    // 37.75 MB
  unsigned short* xn   = (unsigned short*)(ws);         // LIVE until k_final
  unsigned short* Lt   = (unsigned short*)(ws + SZ);
  unsigned short* Rt   = (unsigned short*)(ws + 2*SZ);
  unsigned short* mid  = (unsigned short*)(ws + 3*SZ);
  unsigned short* Wcat = (unsigned short*)(ws + 4*SZ);
  unsigned short* Wot  = (unsigned short*)(ws + 4*SZ + (size_t)640*128*2);

  k_prep  <<<768, 64, 0, stream>>>(Wl, Wlg, Wr, Wrg, Wog, Wo, Wcat, Wot);
  k_ln_x  <<<MM/4, 256, 0, stream>>>(x, na, nb, xn);
  k_proj  <<<1152, 256, 0, stream>>>(xn, Wcat, bl, blg, br, brg, Lt, Rt);
  k_einsum<<<1152, 256, 0, stream>>>(Rt, Lt, mid);
  k_final <<<dim3(6, 384), 256, 0, stream>>>(mid, xn, Wcat, bog, ona, onb, Wot, bo, out);
}

// Round 7
// 166.706 us; speedup vs baseline: 1.5861x; 1.0806x over previous
//
#include <hip/hip_runtime.h>
#include <hip/hip_bf16.h>

#define NN 384
#define DD 128
#define MM (NN*NN)   // 147456 rows

typedef __attribute__((ext_vector_type(8))) short short8;
typedef __attribute__((ext_vector_type(4))) float f32x4;

__device__ __forceinline__ unsigned short f2bf(float f){
  unsigned u = __float_as_uint(f);
  u += 0x7fffu + ((u >> 16) & 1u);      // RNE
  return (unsigned short)(u >> 16);
}
__device__ __forceinline__ float bf2f(unsigned short u){
  return __uint_as_float(((unsigned)u) << 16);
}
__device__ __forceinline__ float sigm(float x){
  return 1.0f / (1.0f + __expf(-x));
}
__device__ __forceinline__ unsigned cvtpk(float lo, float hi){
  unsigned r;
  asm("v_cvt_pk_bf16_f32 %0, %1, %2" : "=v"(r) : "v"(lo), "v"(hi));
  return r;
}
__device__ __forceinline__ f32x4 mfma16(short8 a, short8 b, f32x4 c){
  return __builtin_amdgcn_mfma_f32_16x16x32_bf16(a, b, c, 0, 0, 0);
}
// async global->LDS, 16B/lane; LDS base wave-uniform (HW adds lane*16)
__device__ __forceinline__ void gll16(const void* g, void* l){
  __builtin_amdgcn_global_load_lds(
      (const __attribute__((address_space(1))) unsigned int*)g,
      (__attribute__((address_space(3))) unsigned int*)l, 16, 0, 0);
}

// ---------------------------------------------------------------------------
// k_prep: Wcat_t[n][k] bf16 = [Wl|Wlg|Wr|Wrg|Wog]^T (n in [0,640)); Wot = Wo^T.
__global__ void k_prep(const float* __restrict__ Wl, const float* __restrict__ Wlg,
                       const float* __restrict__ Wr, const float* __restrict__ Wrg,
                       const float* __restrict__ Wog, const float* __restrict__ Wo,
                       unsigned short* __restrict__ Wcat, unsigned short* __restrict__ Wot){
  int n = blockIdx.x;           // 0..767
  if(n < 640){
    const float* src; int col;
    if(n < 128){ src = Wl;  col = n; }
    else if(n < 256){ src = Wlg; col = n-128; }
    else if(n < 384){ src = Wr;  col = n-256; }
    else if(n < 512){ src = Wrg; col = n-384; }
    else            { src = Wog; col = n-512; }
    for(int k = threadIdx.x; k < 128; k += 64)
      Wcat[n*128 + k] = f2bf(src[k*128 + col]);
  } else {
    int c = n - 640;
    for(int k = threadIdx.x; k < 128; k += 64)
      Wot[c*128 + k] = f2bf(Wo[k*128 + c]);
  }
}

// ---------------------------------------------------------------------------
// k_ln_x: layernorm rows of x (fp32) -> xn bf16.  One wave per row.
__global__ __launch_bounds__(256) void k_ln_x(const float* __restrict__ x,
    const float* __restrict__ na, const float* __restrict__ nb,
    unsigned short* __restrict__ xn){
  int wid = threadIdx.x >> 6, lane = threadIdx.x & 63;
  long r = (long)blockIdx.x*4 + wid;
  float2 v = *(const float2*)(x + r*DD + lane*2);
  float s  = v.x + v.y;
  float sq = v.x*v.x + v.y*v.y;
  #pragma unroll
  for(int m = 32; m >= 1; m >>= 1){ s += __shfl_xor(s, m); sq += __shfl_xor(sq, m); }
  float mean = s  * (1.0f/128.0f);
  float var  = sq * (1.0f/128.0f) - mean*mean;
  float rstd = rsqrtf(var + 1e-5f);
  float2 a = *(const float2*)(na + lane*2);
  float2 b = *(const float2*)(nb + lane*2);
  unsigned pk = (unsigned)f2bf(a.x*(v.x-mean)*rstd + b.x)
              | ((unsigned)f2bf(a.y*(v.y-mean)*rstd + b.y) << 16);
  *(unsigned*)(xn + r*DD + lane*2) = pk;
}

// ---------------------------------------------------------------------------
// k_proj: persistent L/R projection (unchanged from R5/R6).
__global__ __launch_bounds__(256, 4) void k_proj(
    const unsigned short* __restrict__ xn, const unsigned short* __restrict__ Wcat,
    const float* __restrict__ bl, const float* __restrict__ blg,
    const float* __restrict__ br, const float* __restrict__ brg,
    unsigned short* __restrict__ Lt, unsigned short* __restrict__ Rt){
  __shared__ char lds[2][16384];
  const int tid = threadIdx.x;
  const int wid = tid >> 6, lane = tid & 63;
  const int lrow = lane & 15, lgrp = lane >> 4;
  const int b = blockIdx.x;            // 1152 = 4*288
  const int f = b / 288;               // d-quarter
  const int w = b % 288;

  const int ws = wid >> 1;             // 0=L 1=R
  const int wd = wid & 1;              // d-16-half of quarter
  const int d  = f*32 + wd*16 + lrow;

  short8 bv[4], bg[4];
  #pragma unroll
  for(int ks = 0; ks < 4; ++ks){
    bv[ks] = *(const short8*)(Wcat + (ws*256 + d)*DD + ks*32 + lgrp*8);
    bg[ks] = *(const short8*)(Wcat + (ws*256 + 128 + d)*DD + ks*32 + lgrp*8);
  }
  const float b0v = (ws ? br  : bl )[d];
  const float b1v = (ws ? brg : blg)[d];
  const float sc  = ws ? 1.0f : (1.0f/384.0f);   // fold einsum 1/n into Lt
  unsigned short* const base = (ws ? Rt : Lt) + (long)d*MM;

  auto stage = [&](int buf, int v){
    int j = v/6, kb = v%6;
    int rsub = lane >> 4, c = lane & 15;
    #pragma unroll
    for(int p = 0; p < 4; ++p){
      int r0 = p*16 + wid*4;
      int r = r0 + rsub;
      gll16(xn + ((long)(kb*64 + r)*NN + j)*DD + (c ^ (r & 7))*8, &lds[buf][r0*256]);
    }
  };

  stage(0, w*8);
  __syncthreads();
  int cur = 0;
  for(int i = 0; i < 8; ++i){
    int v = w*8 + i;
    if(i < 7) stage(cur^1, v+1);       // prefetch flies over compute+epilogue

    f32x4 zero = {0.f,0.f,0.f,0.f};
    f32x4 acc[4][2];
    #pragma unroll
    for(int a1=0;a1<4;++a1){ acc[a1][0] = zero; acc[a1][1] = zero; }

    #pragma unroll
    for(int ks = 0; ks < 4; ++ks){
      #pragma unroll
      for(int fr = 0; fr < 4; ++fr){
        int r = fr*16 + lrow;
        short8 af = *(const short8*)(&lds[cur][r*256 + (((ks*4+lgrp)*16) ^ ((r&7)<<4))]);
        acc[fr][0] = mfma16(af, bv[ks], acc[fr][0]);
        acc[fr][1] = mfma16(af, bg[ks], acc[fr][1]);
      }
    }

    int j = v/6, kb = v%6;
    unsigned short* dst = base + (long)j*NN + kb*64;
    #pragma unroll
    for(int fr = 0; fr < 4; ++fr){
      float v0 = (acc[fr][0][0] + b0v)*sigm(acc[fr][1][0] + b1v)*sc;
      float v1 = (acc[fr][0][1] + b0v)*sigm(acc[fr][1][1] + b1v)*sc;
      float v2 = (acc[fr][0][2] + b0v)*sigm(acc[fr][1][2] + b1v)*sc;
      float v3 = (acc[fr][0][3] + b0v)*sigm(acc[fr][1][3] + b1v)*sc;
      uint2 pk; pk.x = cvtpk(v0, v1); pk.y = cvtpk(v2, v3);
      *(uint2*)(dst + fr*16 + lgrp*4) = pk;
    }
    __syncthreads();                   // prefetch landed; buffers swap
    cur ^= 1;
  }
}

// ---------------------------------------------------------------------------
// k_einsum: unchanged from R6.
__global__ __launch_bounds__(256) void k_einsum(
    const unsigned short* __restrict__ Rt, const unsigned short* __restrict__ Lt,
    unsigned short* __restrict__ mid){
  __shared__ char lds[65536];
  const int b = blockIdx.x;              // 1152 = 8 * 144
  const int xcd = b & 7, slot = b >> 3;
  const int d = (slot/9)*8 + xcd;
  const int t = slot % 9;
  const int it = t/3, jt = t%3;
  const int i0 = it*128, j0 = jt*128;
  const unsigned short* Abase = Lt + (long)d*MM;   // j-rows
  const unsigned short* Bbase = Rt + (long)d*MM;   // i-rows
  const int wid = threadIdx.x >> 6, lane = threadIdx.x & 63;
  const int wr = wid >> 1, wc = wid & 1;
  const int lrow = lane & 15, lgrp = lane >> 4;

  auto stage = [&](int buf, int kt){
    int k = kt*64;
    int c = lane & 7;
    #pragma unroll
    for(int t8 = 0; t8 < 8; ++t8){
      int rr = wid*64 + t8*8 + (lane >> 3);   // 0..255 (first 128 = A rows)
      int r = rr & 127;
      const unsigned short* src = (rr < 128) ? (Abase + (long)(j0+r)*NN + k)
                                             : (Bbase + (long)(i0+r)*NN + k);
      gll16(src + (c ^ (r & 7))*8, &lds[buf*32768 + (wid*64 + t8*8)*128]);
    }
  };

  f32x4 zero = {0.f,0.f,0.f,0.f};
  f32x4 acc[4][4];                       // [fj][fi]
  #pragma unroll
  for(int a1 = 0; a1 < 4; ++a1)
    #pragma unroll
    for(int a2 = 0; a2 < 4; ++a2) acc[a1][a2] = zero;

  stage(0, 0);
  __syncthreads();
  for(int kt = 0; kt < 6; ++kt){
    int cur = kt & 1;
    if(kt < 5) stage(cur ^ 1, kt + 1);
    const int base = cur*32768;
    #pragma unroll
    for(int ks = 0; ks < 2; ++ks){
      short8 af[4], bf[4];
      #pragma unroll
      for(int f = 0; f < 4; ++f){
        int rj = wr*64 + f*16 + lrow;
        af[f] = *(const short8*)(&lds[base + rj*128 + (((ks*4+lgrp)*16) ^ ((rj & 7) << 4))]);
        int ri = wc*64 + f*16 + lrow;
        bf[f] = *(const short8*)(&lds[base + 16384 + ri*128 + (((ks*4+lgrp)*16) ^ ((ri & 7) << 4))]);
      }
      #pragma unroll
      for(int fj = 0; fj < 4; ++fj)
        #pragma unroll
        for(int fi = 0; fi < 4; ++fi)
          acc[fj][fi] = mfma16(af[fj], bf[fi], acc[fj][fi]);
    }
    __syncthreads();
  }

  #pragma unroll
  for(int fj = 0; fj < 4; ++fj){
    int j = j0 + wr*64 + fj*16 + lgrp*4;
    #pragma unroll
    for(int fi = 0; fi < 4; ++fi){
      int i = i0 + wc*64 + fi*16 + lrow;
      uint2 pk;
      pk.x = cvtpk(acc[fj][fi][0], acc[fj][fi][1]);
      pk.y = cvtpk(acc[fj][fi][2], acc[fj][fi][3]);
      *(uint2*)(mid + (long)d*MM + (long)i*NN + j) = pk;
    }
  }
}

// ---------------------------------------------------------------------------
// k_final v3: persistent, 768 blocks x 3 units (unit = (i, 64-wide j strip)).
//  Per unit: prefetch next unit's xn (gll16 -> X[nxt]) + mid (uint2 -> regs);
//  write midt from current regs; gate MFMA from X[cur]; gate overwrites
//  X[cur]; LN*gate -> X[cur] in-place; out MFMA (A=Wot rows=c -> float4
//  stores). Wog/Wot frags + bias/LN vectors loaded once per block.
__global__ __launch_bounds__(256, 3) void k_final(
    const unsigned short* __restrict__ mid, const unsigned short* __restrict__ xn,
    const unsigned short* __restrict__ Wcat,
    const float* __restrict__ bog,
    const float* __restrict__ ona, const float* __restrict__ onb,
    const unsigned short* __restrict__ Wot, const float* __restrict__ bo,
    float* __restrict__ out){
  __shared__ char Xb[2][16384];              // xn -> gate -> val, per unit
  __shared__ unsigned short midt[64][136];   // 17.4KB
  __shared__ float clds[512];                // [ona|onb|bog|bo]
  const int tid = threadIdx.x;
  const int wid = tid >> 6, lane = tid & 63;
  const int lrow = lane & 15, lgrp = lane >> 4;
  const int jp = tid & 15, dr = tid >> 4;
  const int u0 = blockIdx.x * 3;

  uint2 mA[8], mB[8];

#define STAGE_XN(buf, uu) {                                                   \
    int i_ = (uu)/6, jj_ = ((uu)%6)*64;                                       \
    int rsub = lane >> 4, cc = lane & 15;                                     \
    _Pragma("unroll")                                                         \
    for(int p = 0; p < 4; ++p){                                               \
      int r0 = p*16 + wid*4;                                                  \
      int r = r0 + rsub;                                                      \
      gll16(xn + ((long)i_*NN + jj_ + r)*DD + (cc ^ (r & 7))*8,               \
            &Xb[buf][r0*256]);                                                \
    } }

#define LOAD_MID(reg, uu) {                                                   \
    int i_ = (uu)/6, jj_ = ((uu)%6)*64;                                       \
    const unsigned short* mp = mid + (long)i_*NN + jj_ + jp*4;                \
    _Pragma("unroll")                                                         \
    for(int p = 0; p < 8; ++p)                                                \
      reg[p] = *(const uint2*)(mp + (long)(p*16 + dr)*MM);                    \
  }

#define WRITE_MIDT(reg) {                                                     \
    _Pragma("unroll")                                                         \
    for(int p = 0; p < 8; ++p){                                               \
      int dd = p*16 + dr;                                                     \
      midt[jp*4+0][dd] = (unsigned short)(reg[p].x & 0xffffu);                \
      midt[jp*4+1][dd] = (unsigned short)(reg[p].x >> 16);                    \
      midt[jp*4+2][dd] = (unsigned short)(reg[p].y & 0xffffu);                \
      midt[jp*4+3][dd] = (unsigned short)(reg[p].y >> 16);                    \
    } }

  // ---- per-block constants
  short8 ag[2][4], aw[2][4];
  #pragma unroll
  for(int cf = 0; cf < 2; ++cf)
    #pragma unroll
    for(int ks = 0; ks < 4; ++ks){
      ag[cf][ks] = *(const short8*)(Wcat + (512 + wid*32 + cf*16 + lrow)*DD + ks*32 + lgrp*8);
      aw[cf][ks] = *(const short8*)(Wot  + (      wid*32 + cf*16 + lrow)*DD + ks*32 + lgrp*8);
    }
  if(tid < 128){
    clds[tid]       = ona[tid];
    clds[128 + tid] = onb[tid];
    clds[256 + tid] = bog[tid];
    clds[384 + tid] = bo[tid];
  }

  STAGE_XN(0, u0);
  LOAD_MID(mA, u0);
  __syncthreads();                          // cold start drained

#define UNIT(T, MREG, MNXT, CUR) {                                            \
    const int u_ = u0 + (T);                                                  \
    const int iU = u_/6, jU = (u_%6)*64;                                      \
    if((T) < 2){ STAGE_XN((CUR)^1, u_+1); LOAD_MID(MNXT, u_+1); }             \
    WRITE_MIDT(MREG);                                                         \
    f32x4 zero_ = {0.f,0.f,0.f,0.f};                                          \
    f32x4 accg[2][4];                                                         \
    _Pragma("unroll")                                                         \
    for(int a1=0;a1<2;++a1){ _Pragma("unroll")                                \
      for(int a2=0;a2<4;++a2) accg[a1][a2] = zero_; }                         \
    _Pragma("unroll")                                                         \
    for(int ks = 0; ks < 4; ++ks){                                            \
      short8 bx[4];                                                           \
      _Pragma("unroll")                                                       \
      for(int mf = 0; mf < 4; ++mf){                                          \
        int r = mf*16 + lrow;                                                 \
        bx[mf] = *(const short8*)(&Xb[CUR][r*256 + (((ks*4+lgrp)*16) ^ ((r&7)<<4))]); \
      }                                                                       \
      _Pragma("unroll")                                                       \
      for(int cf = 0; cf < 2; ++cf){ _Pragma("unroll")                        \
        for(int mf = 0; mf < 4; ++mf)                                         \
          accg[cf][mf] = mfma16(ag[cf][ks], bx[mf], accg[cf][mf]); }          \
    }                                                                         \
    __syncthreads();  /* B1: xn reads done; midt written; prefetch drained */ \
    _Pragma("unroll")                                                         \
    for(int cf = 0; cf < 2; ++cf){                                            \
      int c0 = wid*32 + cf*16 + lgrp*4;                                       \
      float4 g4 = *(const float4*)&clds[256 + c0];                            \
      _Pragma("unroll")                                                       \
      for(int mf = 0; mf < 4; ++mf){                                          \
        int rr = mf*16 + lrow;                                                \
        uint2 pk;                                                             \
        pk.x = cvtpk(sigm(accg[cf][mf][0]+g4.x), sigm(accg[cf][mf][1]+g4.y)); \
        pk.y = cvtpk(sigm(accg[cf][mf][2]+g4.z), sigm(accg[cf][mf][3]+g4.w)); \
        *(uint2*)(&Xb[CUR][rr*256 + ((c0*2) ^ ((rr&7)<<4))]) = pk;            \
      }                                                                       \
    }                                                                         \
    __syncthreads();  /* B2: gate ready */                                    \
    {                                                                         \
      int j_ = tid >> 2, s_ = tid & 3;                                        \
      float sum = 0.f, sq = 0.f;                                              \
      _Pragma("unroll")                                                       \
      for(int o8 = 0; o8 < 4; ++o8){                                          \
        short8 h = *(const short8*)(&midt[j_][s_*32 + o8*8]);                 \
        _Pragma("unroll")                                                     \
        for(int q = 0; q < 8; ++q){                                           \
          float vq = bf2f((unsigned short)h[q]);                              \
          sum += vq; sq += vq*vq;                                             \
        }                                                                     \
      }                                                                       \
      sum += __shfl_xor(sum,1); sq += __shfl_xor(sq,1);                       \
      sum += __shfl_xor(sum,2); sq += __shfl_xor(sq,2);                       \
      float mean = sum*(1.f/128.f);                                           \
      float var  = sq *(1.f/128.f) - mean*mean;                               \
      float rstd = rsqrtf(var + 1e-5f);                                       \
      _Pragma("unroll")                                                       \
      for(int o = 0; o < 32; o += 4){                                         \
        int dd = s_*32 + o;                                                   \
        char* gp = &Xb[CUR][j_*256 + ((dd*2) ^ ((j_&7)<<4))];                 \
        uint2 gv = *(uint2*)gp;                                               \
        uint2 mv = *(const uint2*)(&midt[j_][dd]);                            \
        float m0 = bf2f((unsigned short)(mv.x & 0xffffu));                    \
        float m1 = bf2f((unsigned short)(mv.x >> 16));                        \
        float m2 = bf2f((unsigned short)(mv.y & 0xffffu));                    \
        float m3 = bf2f((unsigned short)(mv.y >> 16));                        \
        float4 a4 = *(const float4*)&clds[dd];                                \
        float4 b4 = *(const float4*)&clds[128 + dd];                          \
        float v0 = (a4.x*(m0-mean)*rstd + b4.x)*bf2f((unsigned short)(gv.x & 0xffffu)); \
        float v1 = (a4.y*(m1-mean)*rstd + b4.y)*bf2f((unsigned short)(gv.x >> 16));     \
        float v2 = (a4.z*(m2-mean)*rstd + b4.z)*bf2f((unsigned short)(gv.y & 0xffffu)); \
        float v3 = (a4.w*(m3-mean)*rstd + b4.w)*bf2f((unsigned short)(gv.y >> 16));     \
        uint2 pk; pk.x = cvtpk(v0, v1); pk.y = cvtpk(v2, v3);                 \
        *(uint2*)gp = pk;                                                     \
      }                                                                       \
    }                                                                         \
    __syncthreads();  /* B3: val ready */                                     \
    {                                                                         \
      f32x4 acco[2][4];                                                       \
      _Pragma("unroll")                                                       \
      for(int a1=0;a1<2;++a1){ _Pragma("unroll")                              \
        for(int a2=0;a2<4;++a2) acco[a1][a2] = zero_; }                       \
      _Pragma("unroll")                                                       \
      for(int ks = 0; ks < 4; ++ks){                                          \
        short8 bx[4];                                                         \
        _Pragma("unroll")                                                     \
        for(int mf = 0; mf < 4; ++mf){                                        \
          int r = mf*16 + lrow;                                               \
          bx[mf] = *(const short8*)(&Xb[CUR][r*256 + (((ks*4+lgrp)*16) ^ ((r&7)<<4))]); \
        }                                                                     \
        _Pragma("unroll")                                                     \
        for(int cf = 0; cf < 2; ++cf){ _Pragma("unroll")                      \
          for(int mf = 0; mf < 4; ++mf)                                       \
            acco[cf][mf] = mfma16(aw[cf][ks], bx[mf], acco[cf][mf]); }        \
      }                                                                       \
      _Pragma("unroll")                                                       \
      for(int cf = 0; cf < 2; ++cf){                                          \
        int c0 = wid*32 + cf*16 + lgrp*4;                                     \
        float4 b4 = *(const float4*)&clds[384 + c0];                          \
        _Pragma("unroll")                                                     \
        for(int mf = 0; mf < 4; ++mf){                                        \
          int jl = mf*16 + lrow;                                              \
          float4 v;                                                           \
          v.x = acco[cf][mf][0] + b4.x;                                       \
          v.y = acco[cf][mf][1] + b4.y;                                       \
          v.z = acco[cf][mf][2] + b4.z;                                       \
          v.w = acco[cf][mf][3] + b4.w;                                       \
          *(float4*)(out + ((long)iU*NN + jU + jl)*DD + c0) = v;              \
        }                                                                     \
      }                                                                       \
    }                                                                         \
    __syncthreads();  /* B4: val reads done before next unit stages over it */\
  }

  UNIT(0, mA, mB, 0)
  UNIT(1, mB, mA, 1)
  UNIT(2, mA, mB, 0)

#undef UNIT
#undef STAGE_XN
#undef LOAD_MID
#undef WRITE_MIDT
}

// ---------------------------------------------------------------------------
extern "C" void kernel_launch(void* const* d_in, const int* in_sizes, int n_in,
                              void* d_out, int out_size, void* d_ws, size_t ws_size,
                              hipStream_t stream){
  const float* x   = (const float*)d_in[0];
  const float* na  = (const float*)d_in[1];
  const float* nb  = (const float*)d_in[2];
  const float* Wl  = (const float*)d_in[3];
  const float* bl  = (const float*)d_in[4];
  const float* Wr  = (const float*)d_in[5];
  const float* br  = (const float*)d_in[6];
  const float* Wlg = (const float*)d_in[7];
  const float* blg = (const float*)d_in[8];
  const float* Wrg = (const float*)d_in[9];
  const float* brg = (const float*)d_in[10];
  const float* Wog = (const float*)d_in[11];
  const float* bog = (const float*)d_in[12];
  const float* ona = (const float*)d_in[13];
  const float* onb = (const float*)d_in[14];
  const float* Wo  = (const float*)d_in[15];
  const float* bo  = (const float*)d_in[16];
  float* out = (float*)d_out;

  char* ws = (char*)d_ws;
  const size_t SZ = (size_t)MM*DD*2;                    // 37.75 MB
  unsigned short* xn   = (unsigned short*)(ws);         // LIVE until k_final
  unsigned short* Lt   = (unsigned short*)(ws + SZ);
  unsigned short* Rt   = (unsigned short*)(ws + 2*SZ);
  unsigned short* mid  = (unsigned short*)(ws + 3*SZ);
  unsigned short* Wcat = (unsigned short*)(ws + 4*SZ);
  unsigned short* Wot  = (unsigned short*)(ws + 4*SZ + (size_t)640*128*2);

  k_prep  <<<768, 64, 0, stream>>>(Wl, Wlg, Wr, Wrg, Wog, Wo, Wcat, Wot);
  k_ln_x  <<<MM/4, 256, 0, stream>>>(x, na, nb, xn);
  k_proj  <<<1152, 256, 0, stream>>>(xn, Wcat, bl, blg, br, brg, Lt, Rt);
  k_einsum<<<1152, 256, 0, stream>>>(Rt, Lt, mid);
  k_final <<<768, 256, 0, stream>>>(mid, xn, Wcat, bog, ona, onb, Wot, bo, out);
}